// Round 3
// baseline (817.796 us; speedup 1.0000x reference)
//
#include <hip/hip_runtime.h>
#include <math.h>

// Problem constants (from reference)
#define NODES   1050000
#define EDGES   2100000
#define GRAPHS  50000
#define NPG     21      // nodes per graph
#define NCLS    26

// ---------------------------------------------------------------------------
// Stage 0: in-degree count over dst (self-loop added as +1 later)
__global__ void count_deg(const int* __restrict__ dst, int* __restrict__ cnt) {
    int e = blockIdx.x * blockDim.x + threadIdx.x;
    if (e < EDGES) atomicAdd(&cnt[dst[e]], 1);
}

// Stage 1: dinv = rsqrt(deg+1); u = dinv*x (float2); a1 init = u (self-loop)
__global__ void init_nodes(const float* __restrict__ x, const int* __restrict__ cnt,
                           float* __restrict__ dinv, float2* __restrict__ u,
                           float2* __restrict__ a1) {
    int i = blockIdx.x * blockDim.x + threadIdx.x;
    if (i < NODES) {
        float d = 1.0f / sqrtf((float)(cnt[i] + 1));
        dinv[i] = d;
        float2 xv = ((const float2*)x)[i];
        float2 uv = make_float2(d * xv.x, d * xv.y);
        u[i]  = uv;
        a1[i] = uv;
    }
}

// Stage 2: conv1 aggregation in 2-wide input space: a1[dst] += u[src]
__global__ void edge1(const int* __restrict__ src, const int* __restrict__ dst,
                      const float2* __restrict__ u, float* __restrict__ a1) {
    int e = blockIdx.x * blockDim.x + threadIdx.x;
    if (e < EDGES) {
        int s = src[e], d = dst[e];
        float2 uv = u[s];
        atomicAdd(&a1[2 * d],     uv.x);
        atomicAdd(&a1[2 * d + 1], uv.y);
    }
}

// Stage 3: z4[i] = (z0, z1, dinv_i, 0) with z = dinv_i * a1_i  (conv1 pre-matmul out)
__global__ void node_z(const float2* __restrict__ a1, const float* __restrict__ dinv,
                       float4* __restrict__ z4) {
    int i = blockIdx.x * blockDim.x + threadIdx.x;
    if (i < NODES) {
        float d = dinv[i];
        float2 a = a1[i];
        z4[i] = make_float4(d * a.x, d * a.y, d, 0.0f);
    }
}

// Stage 4 (tiny): wcomb = W2@Wfc [64,26]; bcomb = b2@Wfc + bfc [26]
__global__ void make_wcomb(const float* __restrict__ W2, const float* __restrict__ b2,
                           const float* __restrict__ Wfc, const float* __restrict__ bfc,
                           float* __restrict__ wcomb, float* __restrict__ bcomb) {
    int t = blockIdx.x * blockDim.x + threadIdx.x;
    if (t < 64 * NCLS) {
        int f = t / NCLS, c = t % NCLS;
        float acc = 0.f;
        for (int k = 0; k < 128; ++k) acc += W2[f * 128 + k] * Wfc[k * NCLS + c];
        wcomb[t] = acc;
    } else if (t < 64 * NCLS + NCLS) {
        int c = t - 64 * NCLS;
        float acc = bfc[c];
        for (int k = 0; k < 128; ++k) acc += b2[k] * Wfc[k * NCLS + c];
        bcomb[c] = acc;
    }
}

// Stage 5: self-loop contributions, one wave per graph, NO atomics:
//   pooled[g][f] = sum_{i in g} dinv_i^2 * relu(z0*W1[0][f] + z1*W1[1][f] + b1[f])
__global__ void pool_self(const float4* __restrict__ z4,
                          const float* __restrict__ W1, const float* __restrict__ b1,
                          float* __restrict__ pooled) {
    int lane = threadIdx.x & 63;
    int wv   = threadIdx.x >> 6;
    int g    = blockIdx.x * 4 + wv;
    if (g >= GRAPHS) return;
    float w0 = W1[lane], w1 = W1[64 + lane], bb = b1[lane];
    float acc = 0.f;
    int base = g * NPG;
    #pragma unroll
    for (int n = 0; n < NPG; ++n) {
        float4 z = z4[base + n];
        float h = fmaxf(z.x * w0 + z.y * w1 + bb, 0.0f);
        acc += z.z * z.z * h;
    }
    pooled[(size_t)g * 64 + lane] = acc;
}

// Stage 6: edge contributions, one wave per edge (grid-strided):
//   pooled[g(d)][f] += dinv_s * dinv_d * relu(z_s @ W1 + b1)[f]
__global__ void edge2(const int* __restrict__ src, const int* __restrict__ dst,
                      const float4* __restrict__ z4,
                      const float* __restrict__ W1, const float* __restrict__ b1,
                      float* __restrict__ pooled) {
    int lane  = threadIdx.x & 63;
    int wv    = threadIdx.x >> 6;
    int wid   = blockIdx.x * 4 + wv;           // wave id
    int nwave = gridDim.x * 4;
    float w0 = W1[lane], w1 = W1[64 + lane], bb = b1[lane];
    for (int e = wid; e < EDGES; e += nwave) {
        int s = src[e], d = dst[e];
        float4 zs = z4[s];
        float dd  = z4[d].z;
        float h   = fmaxf(zs.x * w0 + zs.y * w1 + bb, 0.0f);
        int g = d / 21;
        atomicAdd(&pooled[(size_t)g * 64 + lane], h * zs.z * dd);
    }
}

// Stage 7: per graph: ps = pooled/21; logits = ps@wcomb + bcomb; log_softmax
__global__ void final_k(const float* __restrict__ pooled,
                        const float* __restrict__ wcomb, const float* __restrict__ bcomb,
                        float* __restrict__ out) {
    __shared__ float ps[4][64];
    int lane = threadIdx.x & 63;
    int wv   = threadIdx.x >> 6;
    int g    = blockIdx.x * 4 + wv;
    if (g >= GRAPHS) return;

    ps[wv][lane] = pooled[(size_t)g * 64 + lane] * (1.0f / (float)NPG);
    __syncthreads();

    float logit = 0.f;
    if (lane < NCLS) {
        logit = bcomb[lane];
        #pragma unroll
        for (int f = 0; f < 64; ++f) logit += ps[wv][f] * wcomb[f * NCLS + lane];
    }
    float m = (lane < NCLS) ? logit : -INFINITY;
    #pragma unroll
    for (int off = 32; off; off >>= 1) m = fmaxf(m, __shfl_xor(m, off, 64));
    float ex = (lane < NCLS) ? expf(logit - m) : 0.f;
    float s = ex;
    #pragma unroll
    for (int off = 32; off; off >>= 1) s += __shfl_xor(s, off, 64);
    if (lane < NCLS) out[g * NCLS + lane] = logit - m - logf(s);
}

// ---------------------------------------------------------------------------
extern "C" void kernel_launch(void* const* d_in, const int* in_sizes, int n_in,
                              void* d_out, int out_size, void* d_ws, size_t ws_size,
                              hipStream_t stream) {
    const float* x   = (const float*)d_in[0];
    const int*   src = (const int*)  d_in[1];
    const int*   dst = (const int*)  d_in[2];
    // d_in[3] = batch (unused; batch == i/21 by construction)
    const float* W1  = (const float*)d_in[4];
    const float* b1  = (const float*)d_in[5];
    const float* W2  = (const float*)d_in[6];
    const float* b2  = (const float*)d_in[7];
    const float* Wfc = (const float*)d_in[8];
    const float* bfc = (const float*)d_in[9];
    float* out = (float*)d_out;

    // workspace carve-up (256B aligned) — total ~55 MB
    char* ws = (char*)d_ws;
    size_t off = 0;
    auto carve = [&](size_t bytes) { char* p = ws + off; off += (bytes + 255) & ~(size_t)255; return p; };
    int*    cnt    = (int*)   carve((size_t)NODES * 4);            //  4.2 MB
    float*  dinv   = (float*) carve((size_t)NODES * 4);            //  4.2 MB
    float2* u      = (float2*)carve((size_t)NODES * 8);            //  8.4 MB
    float2* a1     = (float2*)carve((size_t)NODES * 8);            //  8.4 MB
    float4* z4     = (float4*)carve((size_t)NODES * 16);           // 16.8 MB
    float*  pooled = (float*) carve((size_t)GRAPHS * 64 * 4);      // 12.8 MB
    float*  wcomb  = (float*) carve((size_t)64 * NCLS * 4);
    float*  bcomb  = (float*) carve((size_t)NCLS * 4);
    (void)ws_size;

    hipMemsetAsync(cnt, 0, (size_t)NODES * 4, stream);

    count_deg <<<(EDGES + 255) / 256, 256, 0, stream>>>(dst, cnt);
    init_nodes<<<(NODES + 255) / 256, 256, 0, stream>>>(x, cnt, dinv, u, a1);
    edge1     <<<(EDGES + 255) / 256, 256, 0, stream>>>(src, dst, u, (float*)a1);
    node_z    <<<(NODES + 255) / 256, 256, 0, stream>>>(a1, dinv, z4);
    make_wcomb<<<(64 * NCLS + NCLS + 255) / 256, 256, 0, stream>>>(W2, b2, Wfc, bfc, wcomb, bcomb);
    pool_self <<<(GRAPHS + 3) / 4, 256, 0, stream>>>(z4, W1, b1, pooled);
    edge2     <<<4096, 256, 0, stream>>>(src, dst, z4, W1, b1, pooled);
    final_k   <<<(GRAPHS + 3) / 4, 256, 0, stream>>>(pooled, wcomb, bcomb, out);
}

// Round 4
// 573.219 us; speedup vs baseline: 1.4267x; 1.4267x over previous
//
#include <hip/hip_runtime.h>
#include <math.h>

// Problem constants (from reference)
#define NODES   1050000
#define EDGES   2100000
#define GRAPHS  50000
#define NPG     21      // nodes per graph
#define NCLS    26
#define NCHUNK  ((GRAPHS + 1023) / 1024)   // 49 scan chunks

// ---------------------------------------------------------------------------
// S1: per-node in-degree (for dinv) + per-graph incoming-edge count (for sort)
__global__ void count_k(const int* __restrict__ dst, int* __restrict__ cnt,
                        int* __restrict__ ecnt) {
    int e = blockIdx.x * blockDim.x + threadIdx.x;
    if (e < EDGES) {
        int d = dst[e];
        atomicAdd(&cnt[d], 1);
        atomicAdd(&ecnt[d / NPG], 1);
    }
}

// S2a: per-1024-chunk exclusive scan of ecnt -> eoff; chunk totals -> btot
__global__ void scan1_k(const int* __restrict__ ecnt, int* __restrict__ eoff,
                        int* __restrict__ btot) {
    __shared__ int tmp[1024];
    int i = blockIdx.x * 1024 + threadIdx.x;
    int v = (i < GRAPHS) ? ecnt[i] : 0;
    tmp[threadIdx.x] = v;
    __syncthreads();
    for (int off = 1; off < 1024; off <<= 1) {
        int t = (threadIdx.x >= off) ? tmp[threadIdx.x - off] : 0;
        __syncthreads();
        tmp[threadIdx.x] += t;
        __syncthreads();
    }
    if (i < GRAPHS) eoff[i] = tmp[threadIdx.x] - v;   // exclusive
    if (threadIdx.x == 1023) btot[blockIdx.x] = tmp[1023];
}

// S2b: add chunk-total prefix to each chunk's offsets
__global__ void scan2_k(const int* __restrict__ btot, int* __restrict__ eoff) {
    int pre = 0;
    for (int j = 0; j < (int)blockIdx.x; ++j) pre += btot[j];
    int i = blockIdx.x * 1024 + threadIdx.x;
    if (i < GRAPHS) eoff[i] += pre;
}

// S3: scatter edges into graph-sorted order (payload = (src,dst))
__global__ void scatter_k(const int* __restrict__ src, const int* __restrict__ dst,
                          const int* __restrict__ eoff, int* __restrict__ ecur,
                          int2* __restrict__ sortedE) {
    int e = blockIdx.x * blockDim.x + threadIdx.x;
    if (e < EDGES) {
        int s = src[e], d = dst[e];
        int g = d / NPG;
        int pos = eoff[g] + atomicAdd(&ecur[g], 1);
        sortedE[pos] = make_int2(s, d);
    }
}

// S4: dinv = rsqrt(deg+1); u = dinv * x
__global__ void init_nodes(const float* __restrict__ x, const int* __restrict__ cnt,
                           float* __restrict__ dinv, float2* __restrict__ u) {
    int i = blockIdx.x * blockDim.x + threadIdx.x;
    if (i < NODES) {
        float d = 1.0f / sqrtf((float)(cnt[i] + 1));
        dinv[i] = d;
        float2 xv = ((const float2*)x)[i];
        u[i] = make_float2(d * xv.x, d * xv.y);
    }
}

// S5 (tiny): wcomb = W2@Wfc [64,26]; bcomb = b2@Wfc + bfc [26]
__global__ void make_wcomb(const float* __restrict__ W2, const float* __restrict__ b2,
                           const float* __restrict__ Wfc, const float* __restrict__ bfc,
                           float* __restrict__ wcomb, float* __restrict__ bcomb) {
    int t = blockIdx.x * blockDim.x + threadIdx.x;
    if (t < 64 * NCLS) {
        int f = t / NCLS, c = t % NCLS;
        float acc = 0.f;
        for (int k = 0; k < 128; ++k) acc += W2[f * 128 + k] * Wfc[k * NCLS + c];
        wcomb[t] = acc;
    } else if (t < 64 * NCLS + NCLS) {
        int c = t - 64 * NCLS;
        float acc = bfc[c];
        for (int k = 0; k < 128; ++k) acc += b2[k] * Wfc[k * NCLS + c];
        bcomb[c] = acc;
    }
}

// S6: conv1 per graph — LDS accumulation of a1[d] = u[d] + sum u[src], then
//     z4[i] = (dinv*a1.x, dinv*a1.y, dinv, 0). One wave per graph, 4/block.
__global__ void conv1_k(const int2* __restrict__ sortedE, const int* __restrict__ eoff,
                        const int* __restrict__ ecnt, const float2* __restrict__ u,
                        const float* __restrict__ dinv, float4* __restrict__ z4) {
    __shared__ float a1loc[4][NPG][2];
    int lane = threadIdx.x & 63, wv = threadIdx.x >> 6;
    int g    = blockIdx.x * 4 + wv;
    int base = g * NPG;
    if (lane < 2 * NPG) {                       // self-loop init
        int n = lane >> 1, c = lane & 1;
        float2 uv = u[base + n];
        a1loc[wv][n][c] = c ? uv.y : uv.x;
    }
    __syncthreads();
    int off = eoff[g], cg = ecnt[g];
    for (int i = lane; i < cg; i += 64) {
        int2 sd = sortedE[off + i];
        float2 uv = u[sd.x];
        atomicAdd(&a1loc[wv][sd.y - base][0], uv.x);
        atomicAdd(&a1loc[wv][sd.y - base][1], uv.y);
    }
    __syncthreads();
    if (lane < NPG) {
        float dv = dinv[base + lane];
        z4[base + lane] = make_float4(dv * a1loc[wv][lane][0],
                                      dv * a1loc[wv][lane][1], dv, 0.0f);
    }
}

// S7: conv2 + mean-pool + FC + log_softmax fused, per graph (one wave each).
//   acc[f] = sum_self dinv^2*h[i][f] + sum_edges dinv_s*dinv_d*h[s][f]
//   logits = (acc/21) @ wcomb + bcomb; out = log_softmax(logits)
__global__ void conv2pool_k(const int2* __restrict__ sortedE, const int* __restrict__ eoff,
                            const int* __restrict__ ecnt, const float4* __restrict__ z4,
                            const float* __restrict__ W1, const float* __restrict__ b1,
                            const float* __restrict__ wcomb, const float* __restrict__ bcomb,
                            float* __restrict__ out) {
    __shared__ float dloc[4][NPG];
    __shared__ float ps[4][64];
    int lane = threadIdx.x & 63, wv = threadIdx.x >> 6;
    int g    = blockIdx.x * 4 + wv;
    int base = g * NPG;
    float w0 = W1[lane], w1 = W1[64 + lane], bb = b1[lane];
    float acc = 0.f;
    #pragma unroll
    for (int n = 0; n < NPG; ++n) {             // self-loop contributions
        float4 z = z4[base + n];
        if (lane == 0) dloc[wv][n] = z.z;
        float h = fmaxf(z.x * w0 + z.y * w1 + bb, 0.0f);
        acc += z.z * z.z * h;
    }
    int off = eoff[g], cg = ecnt[g];
    for (int i = 0; i < cg; ++i) {              // edge contributions (no atomics)
        int2 sd = sortedE[off + i];
        float4 zs = z4[sd.x];
        float dd  = dloc[wv][sd.y - base];
        float h   = fmaxf(zs.x * w0 + zs.y * w1 + bb, 0.0f);
        acc += zs.z * dd * h;
    }
    ps[wv][lane] = acc * (1.0f / (float)NPG);
    __syncthreads();
    float logit = 0.f;
    if (lane < NCLS) {
        logit = bcomb[lane];
        #pragma unroll
        for (int f = 0; f < 64; ++f) logit += ps[wv][f] * wcomb[f * NCLS + lane];
    }
    float m = (lane < NCLS) ? logit : -INFINITY;
    #pragma unroll
    for (int o = 32; o; o >>= 1) m = fmaxf(m, __shfl_xor(m, o, 64));
    float ex = (lane < NCLS) ? expf(logit - m) : 0.f;
    float s = ex;
    #pragma unroll
    for (int o = 32; o; o >>= 1) s += __shfl_xor(s, o, 64);
    if (lane < NCLS) out[g * NCLS + lane] = logit - m - logf(s);
}

// ---------------------------------------------------------------------------
extern "C" void kernel_launch(void* const* d_in, const int* in_sizes, int n_in,
                              void* d_out, int out_size, void* d_ws, size_t ws_size,
                              hipStream_t stream) {
    const float* x   = (const float*)d_in[0];
    const int*   src = (const int*)  d_in[1];
    const int*   dst = (const int*)  d_in[2];
    // d_in[3] = batch (unused; batch == i/21 by construction)
    const float* W1  = (const float*)d_in[4];
    const float* b1  = (const float*)d_in[5];
    const float* W2  = (const float*)d_in[6];
    const float* b2  = (const float*)d_in[7];
    const float* Wfc = (const float*)d_in[8];
    const float* bfc = (const float*)d_in[9];
    float* out = (float*)d_out;

    // workspace carve-up (256B aligned) — total ~51.5 MB
    char* ws = (char*)d_ws;
    size_t off = 0;
    auto carve = [&](size_t bytes) { char* p = ws + off; off += (bytes + 255) & ~(size_t)255; return p; };
    int*    cnt     = (int*)   carve((size_t)NODES * 4);       //  4.2 MB
    int*    ecnt    = (int*)   carve((size_t)GRAPHS * 4);      //  0.2 MB
    int*    eoff    = (int*)   carve((size_t)GRAPHS * 4);      //  0.2 MB
    int*    ecur    = (int*)   carve((size_t)GRAPHS * 4);      //  0.2 MB
    int*    btot    = (int*)   carve((size_t)NCHUNK * 4);
    float*  dinv    = (float*) carve((size_t)NODES * 4);       //  4.2 MB
    float2* u       = (float2*)carve((size_t)NODES * 8);       //  8.4 MB
    float4* z4      = (float4*)carve((size_t)NODES * 16);      // 16.8 MB
    int2*   sortedE = (int2*)  carve((size_t)EDGES * 8);       // 16.8 MB
    float*  wcomb   = (float*) carve((size_t)64 * NCLS * 4);
    float*  bcomb   = (float*) carve((size_t)NCLS * 4);
    (void)ws_size;

    hipMemsetAsync(cnt,  0, (size_t)NODES * 4, stream);
    hipMemsetAsync(ecnt, 0, (size_t)GRAPHS * 4, stream);
    hipMemsetAsync(ecur, 0, (size_t)GRAPHS * 4, stream);

    count_k    <<<(EDGES + 255) / 256, 256, 0, stream>>>(dst, cnt, ecnt);
    scan1_k    <<<NCHUNK, 1024, 0, stream>>>(ecnt, eoff, btot);
    scan2_k    <<<NCHUNK, 1024, 0, stream>>>(btot, eoff);
    scatter_k  <<<(EDGES + 255) / 256, 256, 0, stream>>>(src, dst, eoff, ecur, sortedE);
    init_nodes <<<(NODES + 255) / 256, 256, 0, stream>>>(x, cnt, dinv, u);
    make_wcomb <<<(64 * NCLS + NCLS + 255) / 256, 256, 0, stream>>>(W2, b2, Wfc, bfc, wcomb, bcomb);
    conv1_k    <<<GRAPHS / 4, 256, 0, stream>>>(sortedE, eoff, ecnt, u, dinv, z4);
    conv2pool_k<<<GRAPHS / 4, 256, 0, stream>>>(sortedE, eoff, ecnt, z4, W1, b1, wcomb, bcomb, out);
}

// Round 5
// 483.511 us; speedup vs baseline: 1.6914x; 1.1855x over previous
//
#include <hip/hip_runtime.h>
#include <math.h>

// Problem constants (from reference)
#define NODES   1050000
#define EDGES   2100000
#define GRAPHS  50000
#define NPG     21      // nodes per graph
#define NCLS    26
#define NCHUNK  ((GRAPHS + 1023) / 1024)   // 49 scan chunks

// ---------------------------------------------------------------------------
// S1: per-node in-degree only (graph edge counts derived in scan1_k)
__global__ void count_k(const int* __restrict__ dst, int* __restrict__ cnt) {
    int e = blockIdx.x * blockDim.x + threadIdx.x;
    if (e < EDGES) atomicAdd(&cnt[dst[e]], 1);
}

// S2a: ecnt[g] = sum of the graph's 21 node counts; chunk-local exclusive scan
__global__ void scan1_k(const int* __restrict__ cnt, int* __restrict__ ecnt,
                        int* __restrict__ eoff, int* __restrict__ btot) {
    __shared__ int tmp[1024];
    int g = blockIdx.x * 1024 + threadIdx.x;
    int v = 0;
    if (g < GRAPHS) {
        int base = g * NPG;
        #pragma unroll
        for (int n = 0; n < NPG; ++n) v += cnt[base + n];
        ecnt[g] = v;
    }
    tmp[threadIdx.x] = v;
    __syncthreads();
    for (int off = 1; off < 1024; off <<= 1) {
        int t = (threadIdx.x >= off) ? tmp[threadIdx.x - off] : 0;
        __syncthreads();
        tmp[threadIdx.x] += t;
        __syncthreads();
    }
    if (g < GRAPHS) eoff[g] = tmp[threadIdx.x] - v;   // exclusive
    if (threadIdx.x == 1023) btot[blockIdx.x] = tmp[1023];
}

// S2b: add chunk-total prefix
__global__ void scan2_k(const int* __restrict__ btot, int* __restrict__ eoff) {
    int pre = 0;
    for (int j = 0; j < (int)blockIdx.x; ++j) pre += btot[j];
    int i = blockIdx.x * 1024 + threadIdx.x;
    if (i < GRAPHS) eoff[i] += pre;
}

// S3: scatter edges into graph-sorted order, packed: (src<<5) | (dst % 21)
__global__ void scatter_k(const int* __restrict__ src, const int* __restrict__ dst,
                          const int* __restrict__ eoff, int* __restrict__ ecur,
                          int* __restrict__ pe) {
    int e = blockIdx.x * blockDim.x + threadIdx.x;
    if (e < EDGES) {
        int s = src[e], d = dst[e];
        int g = d / NPG;
        int pos = eoff[g] + atomicAdd(&ecur[g], 1);
        pe[pos] = (s << 5) | (d - g * NPG);
    }
}

// S4: dinv = rsqrt(deg+1); u = dinv * x
__global__ void init_nodes(const float* __restrict__ x, const int* __restrict__ cnt,
                           float* __restrict__ dinv, float2* __restrict__ u) {
    int i = blockIdx.x * blockDim.x + threadIdx.x;
    if (i < NODES) {
        float d = 1.0f / sqrtf((float)(cnt[i] + 1));
        dinv[i] = d;
        float2 xv = ((const float2*)x)[i];
        u[i] = make_float2(d * xv.x, d * xv.y);
    }
}

// S5 (tiny): wcomb = W2@Wfc [64,26]; bcomb = b2@Wfc + bfc [26]
__global__ void make_wcomb(const float* __restrict__ W2, const float* __restrict__ b2,
                           const float* __restrict__ Wfc, const float* __restrict__ bfc,
                           float* __restrict__ wcomb, float* __restrict__ bcomb) {
    int t = blockIdx.x * blockDim.x + threadIdx.x;
    if (t < 64 * NCLS) {
        int f = t / NCLS, c = t % NCLS;
        float acc = 0.f;
        for (int k = 0; k < 128; ++k) acc += W2[f * 128 + k] * Wfc[k * NCLS + c];
        wcomb[t] = acc;
    } else if (t < 64 * NCLS + NCLS) {
        int c = t - 64 * NCLS;
        float acc = bfc[c];
        for (int k = 0; k < 128; ++k) acc += b2[k] * Wfc[k * NCLS + c];
        bcomb[c] = acc;
    }
}

// S6: conv1 per graph — LDS accumulation, then z4 = (dinv*a1, dinv). 4 graphs/block.
__global__ void conv1_k(const int* __restrict__ pe, const int* __restrict__ eoff,
                        const int* __restrict__ ecnt, const float2* __restrict__ u,
                        const float* __restrict__ dinv, float4* __restrict__ z4) {
    __shared__ float a1loc[4][NPG][2];
    int lane = threadIdx.x & 63, wv = threadIdx.x >> 6;
    int g    = blockIdx.x * 4 + wv;
    int base = g * NPG;
    if (lane < 2 * NPG) {                       // self-loop init
        int n = lane >> 1, c = lane & 1;
        float2 uv = u[base + n];
        a1loc[wv][n][c] = c ? uv.y : uv.x;
    }
    __syncthreads();
    int off = eoff[g], cg = ecnt[g];
    for (int i = lane; i < cg; i += 64) {
        int p = pe[off + i];
        float2 uv = u[p >> 5];
        atomicAdd(&a1loc[wv][p & 31][0], uv.x);
        atomicAdd(&a1loc[wv][p & 31][1], uv.y);
    }
    __syncthreads();
    if (lane < NPG) {
        float dv = dinv[base + lane];
        z4[base + lane] = make_float4(dv * a1loc[wv][lane][0],
                                      dv * a1loc[wv][lane][1], dv, 0.0f);
    }
}

// S7: conv2 + mean-pool + FC + log_softmax fused. ONE graph per block,
// 4 waves split the edge list (serial depth ~11), 2-way unrolled gathers.
__global__ void conv2pool_k(const int* __restrict__ pe, const int* __restrict__ eoff,
                            const int* __restrict__ ecnt, const float4* __restrict__ z4,
                            const float* __restrict__ W1, const float* __restrict__ b1,
                            const float* __restrict__ wcomb, const float* __restrict__ bcomb,
                            float* __restrict__ out) {
    __shared__ float dloc[NPG];
    __shared__ float ps[4][64];
    int lane = threadIdx.x & 63, wv = threadIdx.x >> 6;
    int g    = blockIdx.x;
    int base = g * NPG;
    float w0 = W1[lane], w1 = W1[64 + lane], bb = b1[lane];
    float acc = 0.f;
    // self-loop contributions, nodes strided across the 4 waves
    for (int n = wv; n < NPG; n += 4) {
        float4 z = z4[base + n];
        if (lane == 0) dloc[n] = z.z;
        acc += z.z * z.z * fmaxf(z.x * w0 + z.y * w1 + bb, 0.0f);
    }
    __syncthreads();
    // edge contributions: contiguous quarter per wave, 2-way unroll
    int off = eoff[g], cg = ecnt[g];
    int i    = (cg * wv) >> 2;
    int iend = (cg * (wv + 1)) >> 2;
    for (; i + 2 <= iend; i += 2) {
        int p0 = pe[off + i], p1 = pe[off + i + 1];
        float4 za = z4[p0 >> 5];
        float4 zb = z4[p1 >> 5];
        float ha = fmaxf(za.x * w0 + za.y * w1 + bb, 0.0f);
        float hb = fmaxf(zb.x * w0 + zb.y * w1 + bb, 0.0f);
        acc += za.z * dloc[p0 & 31] * ha + zb.z * dloc[p1 & 31] * hb;
    }
    if (i < iend) {
        int p0 = pe[off + i];
        float4 za = z4[p0 >> 5];
        acc += za.z * dloc[p0 & 31] * fmaxf(za.x * w0 + za.y * w1 + bb, 0.0f);
    }
    ps[wv][lane] = acc;
    __syncthreads();
    if (wv == 0)
        ps[0][lane] = (ps[0][lane] + ps[1][lane] + ps[2][lane] + ps[3][lane])
                      * (1.0f / (float)NPG);
    __syncthreads();
    if (wv == 0) {
        float logit = 0.f;
        if (lane < NCLS) {
            logit = bcomb[lane];
            #pragma unroll
            for (int f = 0; f < 64; ++f) logit += ps[0][f] * wcomb[f * NCLS + lane];
        }
        float m = (lane < NCLS) ? logit : -INFINITY;
        #pragma unroll
        for (int o = 32; o; o >>= 1) m = fmaxf(m, __shfl_xor(m, o, 64));
        float ex = (lane < NCLS) ? expf(logit - m) : 0.f;
        float s = ex;
        #pragma unroll
        for (int o = 32; o; o >>= 1) s += __shfl_xor(s, o, 64);
        if (lane < NCLS) out[g * NCLS + lane] = logit - m - logf(s);
    }
}

// ---------------------------------------------------------------------------
extern "C" void kernel_launch(void* const* d_in, const int* in_sizes, int n_in,
                              void* d_out, int out_size, void* d_ws, size_t ws_size,
                              hipStream_t stream) {
    const float* x   = (const float*)d_in[0];
    const int*   src = (const int*)  d_in[1];
    const int*   dst = (const int*)  d_in[2];
    // d_in[3] = batch (unused; batch == i/21 by construction)
    const float* W1  = (const float*)d_in[4];
    const float* b1  = (const float*)d_in[5];
    const float* W2  = (const float*)d_in[6];
    const float* b2  = (const float*)d_in[7];
    const float* Wfc = (const float*)d_in[8];
    const float* bfc = (const float*)d_in[9];
    float* out = (float*)d_out;

    // workspace carve-up (256B aligned) — total ~42.6 MB
    char* ws = (char*)d_ws;
    size_t off = 0;
    auto carve = [&](size_t bytes) { char* p = ws + off; off += (bytes + 255) & ~(size_t)255; return p; };
    int*    cnt   = (int*)   carve((size_t)NODES * 4);       //  4.2 MB
    int*    ecnt  = (int*)   carve((size_t)GRAPHS * 4);      //  0.2 MB
    int*    eoff  = (int*)   carve((size_t)GRAPHS * 4);      //  0.2 MB
    int*    ecur  = (int*)   carve((size_t)GRAPHS * 4);      //  0.2 MB
    int*    btot  = (int*)   carve((size_t)NCHUNK * 4);
    float*  dinv  = (float*) carve((size_t)NODES * 4);       //  4.2 MB
    float2* u     = (float2*)carve((size_t)NODES * 8);       //  8.4 MB
    float4* z4    = (float4*)carve((size_t)NODES * 16);      // 16.8 MB
    int*    pe    = (int*)   carve((size_t)EDGES * 4);       //  8.4 MB
    float*  wcomb = (float*) carve((size_t)64 * NCLS * 4);
    float*  bcomb = (float*) carve((size_t)NCLS * 4);
    (void)ws_size;

    hipMemsetAsync(cnt,  0, (size_t)NODES * 4, stream);
    hipMemsetAsync(ecur, 0, (size_t)GRAPHS * 4, stream);

    count_k    <<<(EDGES + 255) / 256, 256, 0, stream>>>(dst, cnt);
    scan1_k    <<<NCHUNK, 1024, 0, stream>>>(cnt, ecnt, eoff, btot);
    scan2_k    <<<NCHUNK, 1024, 0, stream>>>(btot, eoff);
    scatter_k  <<<(EDGES + 255) / 256, 256, 0, stream>>>(src, dst, eoff, ecur, pe);
    init_nodes <<<(NODES + 255) / 256, 256, 0, stream>>>(x, cnt, dinv, u);
    make_wcomb <<<(64 * NCLS + NCLS + 255) / 256, 256, 0, stream>>>(W2, b2, Wfc, bfc, wcomb, bcomb);
    conv1_k    <<<GRAPHS / 4, 256, 0, stream>>>(pe, eoff, ecnt, u, dinv, z4);
    conv2pool_k<<<GRAPHS, 256, 0, stream>>>(pe, eoff, ecnt, z4, W1, b1, wcomb, bcomb, out);
}

// Round 6
// 438.161 us; speedup vs baseline: 1.8664x; 1.1035x over previous
//
#include <hip/hip_runtime.h>
#include <hip/hip_fp16.h>
#include <math.h>

// Problem constants (from reference)
#define NODES   1050000
#define EDGES   2100000
#define GRAPHS  50000
#define NPG     21      // nodes per graph
#define NCLS    26
#define NCHUNK  ((GRAPHS + 1023) / 1024)   // 49 scan chunks

// ---------------------------------------------------------------------------
// S1: per-node in-degree only (graph edge counts derived in scan1_k)
__global__ void count_k(const int* __restrict__ dst, int* __restrict__ cnt) {
    int e = blockIdx.x * blockDim.x + threadIdx.x;
    if (e < EDGES) atomicAdd(&cnt[dst[e]], 1);
}

// S2a: ecnt[g] = sum of graph's 21 node counts; chunk-local exclusive scan
__global__ void scan1_k(const int* __restrict__ cnt, int* __restrict__ ecnt,
                        int* __restrict__ eoff, int* __restrict__ btot) {
    __shared__ int tmp[1024];
    int g = blockIdx.x * 1024 + threadIdx.x;
    int v = 0;
    if (g < GRAPHS) {
        int base = g * NPG;
        #pragma unroll
        for (int n = 0; n < NPG; ++n) v += cnt[base + n];
        ecnt[g] = v;
    }
    tmp[threadIdx.x] = v;
    __syncthreads();
    for (int off = 1; off < 1024; off <<= 1) {
        int t = (threadIdx.x >= off) ? tmp[threadIdx.x - off] : 0;
        __syncthreads();
        tmp[threadIdx.x] += t;
        __syncthreads();
    }
    if (g < GRAPHS) eoff[g] = tmp[threadIdx.x] - v;   // exclusive
    if (threadIdx.x == 1023) btot[blockIdx.x] = tmp[1023];
}

// S2b: add chunk-total prefix
__global__ void scan2_k(const int* __restrict__ btot, int* __restrict__ eoff) {
    int pre = 0;
    for (int j = 0; j < (int)blockIdx.x; ++j) pre += btot[j];
    int i = blockIdx.x * 1024 + threadIdx.x;
    if (i < GRAPHS) eoff[i] += pre;
}

// S3: scatter edges into graph-sorted order, packed: (src<<5) | (dst % 21)
__global__ void scatter_k(const int* __restrict__ src, const int* __restrict__ dst,
                          const int* __restrict__ eoff, int* __restrict__ ecur,
                          int* __restrict__ pe) {
    int e = blockIdx.x * blockDim.x + threadIdx.x;
    if (e < EDGES) {
        int s = src[e], d = dst[e];
        int g = d / NPG;
        int pos = eoff[g] + atomicAdd(&ecur[g], 1);
        pe[pos] = (s << 5) | (d - g * NPG);
    }
}

// S4: dinv = rsqrt(deg+1); u packed = half2(dinv*x) (4 B per node)
__global__ void init_nodes(const float* __restrict__ x, const int* __restrict__ cnt,
                           float* __restrict__ dinv, unsigned int* __restrict__ up) {
    int i = blockIdx.x * blockDim.x + threadIdx.x;
    if (i < NODES) {
        float d = 1.0f / sqrtf((float)(cnt[i] + 1));
        dinv[i] = d;
        float2 xv = ((const float2*)x)[i];
        __half2 h = __floats2half2_rn(d * xv.x, d * xv.y);
        up[i] = *reinterpret_cast<unsigned int*>(&h);
    }
}

// S5 (tiny): wcomb = W2@Wfc [64,26]; bcomb = b2@Wfc + bfc [26]
__global__ void make_wcomb(const float* __restrict__ W2, const float* __restrict__ b2,
                           const float* __restrict__ Wfc, const float* __restrict__ bfc,
                           float* __restrict__ wcomb, float* __restrict__ bcomb) {
    int t = blockIdx.x * blockDim.x + threadIdx.x;
    if (t < 64 * NCLS) {
        int f = t / NCLS, c = t % NCLS;
        float acc = 0.f;
        for (int k = 0; k < 128; ++k) acc += W2[f * 128 + k] * Wfc[k * NCLS + c];
        wcomb[t] = acc;
    } else if (t < 64 * NCLS + NCLS) {
        int c = t - 64 * NCLS;
        float acc = bfc[c];
        for (int k = 0; k < 128; ++k) acc += b2[k] * Wfc[k * NCLS + c];
        bcomb[c] = acc;
    }
}

// S6: conv1 per graph — LDS fp32 accumulation of a1 = u[self] + sum u[src];
//     write packed zp[i] = { half2(dinv*a1), fp32 dinv }. 4 graphs/block.
__global__ void conv1_k(const int* __restrict__ pe, const int* __restrict__ eoff,
                        const int* __restrict__ ecnt, const unsigned int* __restrict__ up,
                        const float* __restrict__ dinv, uint2* __restrict__ zp) {
    __shared__ float a1loc[4][NPG][2];
    int lane = threadIdx.x & 63, wv = threadIdx.x >> 6;
    int g    = blockIdx.x * 4 + wv;
    int base = g * NPG;
    if (lane < 2 * NPG) {                       // self-loop init
        int n = lane >> 1, c = lane & 1;
        unsigned int raw = up[base + n];
        __half2 h = *reinterpret_cast<__half2*>(&raw);
        float2 uv = __half22float2(h);
        a1loc[wv][n][c] = c ? uv.y : uv.x;
    }
    __syncthreads();
    int off = eoff[g], cg = ecnt[g];
    for (int i = lane; i < cg; i += 64) {       // 42-wide per-lane random gather
        int p = pe[off + i];
        unsigned int raw = up[p >> 5];
        __half2 h = *reinterpret_cast<__half2*>(&raw);
        float2 uv = __half22float2(h);
        atomicAdd(&a1loc[wv][p & 31][0], uv.x);
        atomicAdd(&a1loc[wv][p & 31][1], uv.y);
    }
    __syncthreads();
    if (lane < NPG) {
        float dv = dinv[base + lane];
        __half2 h = __floats2half2_rn(dv * a1loc[wv][lane][0],
                                      dv * a1loc[wv][lane][1]);
        uint2 w;
        w.x = *reinterpret_cast<unsigned int*>(&h);
        w.y = __float_as_uint(dv);
        zp[base + lane] = w;
    }
}

// S7: conv2 + mean-pool + FC + log_softmax fused.
// 2 graphs/block, 2 waves/graph, 8-deep pipelined broadcast gathers.
__global__ void conv2pool_k(const int* __restrict__ pe, const int* __restrict__ eoff,
                            const int* __restrict__ ecnt, const uint2* __restrict__ zp,
                            const float* __restrict__ W1, const float* __restrict__ b1,
                            const float* __restrict__ wcomb, const float* __restrict__ bcomb,
                            float* __restrict__ out) {
    __shared__ float dloc[2][NPG];
    __shared__ float ps[4][64];
    int lane = threadIdx.x & 63, wv = threadIdx.x >> 6;
    int gi   = wv >> 1;                 // graph index within block (0..1)
    int w01  = wv & 1;                  // wave within graph (0..1)
    int g    = blockIdx.x * 2 + gi;
    int base = g * NPG;
    float w0 = W1[lane], w1 = W1[64 + lane], bb = b1[lane];
    float acc = 0.f;
    // self-loop contributions, nodes strided across the graph's 2 waves
    for (int n = w01; n < NPG; n += 2) {
        uint2 w = zp[base + n];
        __half2 hz = *reinterpret_cast<__half2*>(&w.x);
        float2 z = __half22float2(hz);
        float dv = __uint_as_float(w.y);
        if (lane == 0) dloc[gi][n] = dv;
        acc += dv * dv * fmaxf(z.x * w0 + z.y * w1 + bb, 0.0f);
    }
    __syncthreads();
    // edge contributions: half the edge list per wave, 8-deep pipeline
    int off = eoff[g], cg = ecnt[g];
    int i    = (cg * w01) >> 1;
    int iend = (cg * (w01 + 1)) >> 1;
    for (; i + 8 <= iend; i += 8) {
        int p[8];
        uint2 w[8];
        #pragma unroll
        for (int k = 0; k < 8; ++k) p[k] = pe[off + i + k];
        #pragma unroll
        for (int k = 0; k < 8; ++k) w[k] = zp[p[k] >> 5];
        #pragma unroll
        for (int k = 0; k < 8; ++k) {
            __half2 hz = *reinterpret_cast<__half2*>(&w[k].x);
            float2 z = __half22float2(hz);
            float ds = __uint_as_float(w[k].y);
            acc += ds * dloc[gi][p[k] & 31]
                   * fmaxf(z.x * w0 + z.y * w1 + bb, 0.0f);
        }
    }
    for (; i < iend; ++i) {
        int p = pe[off + i];
        uint2 w = zp[p >> 5];
        __half2 hz = *reinterpret_cast<__half2*>(&w.x);
        float2 z = __half22float2(hz);
        float ds = __uint_as_float(w.y);
        acc += ds * dloc[gi][p & 31]
               * fmaxf(z.x * w0 + z.y * w1 + bb, 0.0f);
    }
    ps[wv][lane] = acc;
    __syncthreads();
    // FC + log_softmax: wave 0 of each graph pair
    if (w01 == 0) {
        float pv = (ps[wv][lane] + ps[wv + 1][lane]) * (1.0f / (float)NPG);
        ps[wv][lane] = pv;
        __builtin_amdgcn_wave_barrier();
        float logit = 0.f;
        if (lane < NCLS) {
            logit = bcomb[lane];
            #pragma unroll
            for (int f = 0; f < 64; ++f) logit += ps[wv][f] * wcomb[f * NCLS + lane];
        }
        float m = (lane < NCLS) ? logit : -INFINITY;
        #pragma unroll
        for (int o = 32; o; o >>= 1) m = fmaxf(m, __shfl_xor(m, o, 64));
        float ex = (lane < NCLS) ? expf(logit - m) : 0.f;
        float s = ex;
        #pragma unroll
        for (int o = 32; o; o >>= 1) s += __shfl_xor(s, o, 64);
        if (lane < NCLS) out[g * NCLS + lane] = logit - m - logf(s);
    }
}

// ---------------------------------------------------------------------------
extern "C" void kernel_launch(void* const* d_in, const int* in_sizes, int n_in,
                              void* d_out, int out_size, void* d_ws, size_t ws_size,
                              hipStream_t stream) {
    const float* x   = (const float*)d_in[0];
    const int*   src = (const int*)  d_in[1];
    const int*   dst = (const int*)  d_in[2];
    // d_in[3] = batch (unused; batch == i/21 by construction)
    const float* W1  = (const float*)d_in[4];
    const float* b1  = (const float*)d_in[5];
    const float* W2  = (const float*)d_in[6];
    const float* b2  = (const float*)d_in[7];
    const float* Wfc = (const float*)d_in[8];
    const float* bfc = (const float*)d_in[9];
    float* out = (float*)d_out;

    // workspace carve-up (256B aligned) — total ~34 MB
    char* ws = (char*)d_ws;
    size_t off = 0;
    auto carve = [&](size_t bytes) { char* p = ws + off; off += (bytes + 255) & ~(size_t)255; return p; };
    int*          cnt   = (int*)          carve((size_t)NODES * 4);    //  4.2 MB
    int*          ecnt  = (int*)          carve((size_t)GRAPHS * 4);   //  0.2 MB
    int*          eoff  = (int*)          carve((size_t)GRAPHS * 4);   //  0.2 MB
    int*          ecur  = (int*)          carve((size_t)GRAPHS * 4);   //  0.2 MB
    int*          btot  = (int*)          carve((size_t)NCHUNK * 4);
    float*        dinv  = (float*)        carve((size_t)NODES * 4);    //  4.2 MB
    unsigned int* up    = (unsigned int*) carve((size_t)NODES * 4);    //  4.2 MB
    uint2*        zp    = (uint2*)        carve((size_t)NODES * 8);    //  8.4 MB
    int*          pe    = (int*)          carve((size_t)EDGES * 4);    //  8.4 MB
    float*        wcomb = (float*)        carve((size_t)64 * NCLS * 4);
    float*        bcomb = (float*)        carve((size_t)NCLS * 4);
    (void)ws_size;

    hipMemsetAsync(cnt,  0, (size_t)NODES * 4, stream);
    hipMemsetAsync(ecur, 0, (size_t)GRAPHS * 4, stream);

    count_k    <<<(EDGES + 255) / 256, 256, 0, stream>>>(dst, cnt);
    scan1_k    <<<NCHUNK, 1024, 0, stream>>>(cnt, ecnt, eoff, btot);
    scan2_k    <<<NCHUNK, 1024, 0, stream>>>(btot, eoff);
    scatter_k  <<<(EDGES + 255) / 256, 256, 0, stream>>>(src, dst, eoff, ecur, pe);
    init_nodes <<<(NODES + 255) / 256, 256, 0, stream>>>(x, cnt, dinv, up);
    make_wcomb <<<(64 * NCLS + NCLS + 255) / 256, 256, 0, stream>>>(W2, b2, Wfc, bfc, wcomb, bcomb);
    conv1_k    <<<GRAPHS / 4, 256, 0, stream>>>(pe, eoff, ecnt, up, dinv, zp);
    conv2pool_k<<<GRAPHS / 2, 256, 0, stream>>>(pe, eoff, ecnt, zp, W1, b1, wcomb, bcomb, out);
}

// Round 7
// 339.540 us; speedup vs baseline: 2.4085x; 1.2905x over previous
//
#include <hip/hip_runtime.h>
#include <hip/hip_fp16.h>
#include <math.h>

// Problem constants (from reference)
#define NODES   1050000
#define EDGES   2100000
#define GRAPHS  50000
#define NPG     21      // nodes per graph
#define NCLS    26
#define NCHUNK  ((GRAPHS + 1023) / 1024)   // 49 scan chunks
#define REC_MAX 168     // per-graph record cap: cg (<=147, Poisson(42)) + 21 self

// ---------------------------------------------------------------------------
// S1: per-node in-degree only (graph edge counts derived in scan1_k)
__global__ void count_k(const int* __restrict__ dst, int* __restrict__ cnt) {
    int e = blockIdx.x * blockDim.x + threadIdx.x;
    if (e < EDGES) atomicAdd(&cnt[dst[e]], 1);
}

// S2a: ecnt[g] = sum of graph's 21 node counts; chunk-local exclusive scan
__global__ void scan1_k(const int* __restrict__ cnt, int* __restrict__ ecnt,
                        int* __restrict__ eoff, int* __restrict__ btot) {
    __shared__ int tmp[1024];
    int g = blockIdx.x * 1024 + threadIdx.x;
    int v = 0;
    if (g < GRAPHS) {
        int base = g * NPG;
        #pragma unroll
        for (int n = 0; n < NPG; ++n) v += cnt[base + n];
        ecnt[g] = v;
    }
    tmp[threadIdx.x] = v;
    __syncthreads();
    for (int off = 1; off < 1024; off <<= 1) {
        int t = (threadIdx.x >= off) ? tmp[threadIdx.x - off] : 0;
        __syncthreads();
        tmp[threadIdx.x] += t;
        __syncthreads();
    }
    if (g < GRAPHS) eoff[g] = tmp[threadIdx.x] - v;   // exclusive
    if (threadIdx.x == 1023) btot[blockIdx.x] = tmp[1023];
}

// S2b: add chunk-total prefix
__global__ void scan2_k(const int* __restrict__ btot, int* __restrict__ eoff) {
    int pre = 0;
    for (int j = 0; j < (int)blockIdx.x; ++j) pre += btot[j];
    int i = blockIdx.x * 1024 + threadIdx.x;
    if (i < GRAPHS) eoff[i] += pre;
}

// S3: scatter edges into graph-sorted order, packed: (src<<5) | (dst % 21)
__global__ void scatter_k(const int* __restrict__ src, const int* __restrict__ dst,
                          const int* __restrict__ eoff, int* __restrict__ ecur,
                          int* __restrict__ pe) {
    int e = blockIdx.x * blockDim.x + threadIdx.x;
    if (e < EDGES) {
        int s = src[e], d = dst[e];
        int g = d / NPG;
        int pos = eoff[g] + atomicAdd(&ecur[g], 1);
        pe[pos] = (s << 5) | (d - g * NPG);
    }
}

// S4: dinv = rsqrt(deg+1); u packed = half2(dinv*x) (4 B per node)
__global__ void init_nodes(const float* __restrict__ x, const int* __restrict__ cnt,
                           float* __restrict__ dinv, unsigned int* __restrict__ up) {
    int i = blockIdx.x * blockDim.x + threadIdx.x;
    if (i < NODES) {
        float d = 1.0f / sqrtf((float)(cnt[i] + 1));
        dinv[i] = d;
        float2 xv = ((const float2*)x)[i];
        __half2 h = __floats2half2_rn(d * xv.x, d * xv.y);
        up[i] = *reinterpret_cast<unsigned int*>(&h);
    }
}

// S5 (tiny): wcomb = W2@Wfc [64,26]; bcomb = b2@Wfc + bfc [26]
__global__ void make_wcomb(const float* __restrict__ W2, const float* __restrict__ b2,
                           const float* __restrict__ Wfc, const float* __restrict__ bfc,
                           float* __restrict__ wcomb, float* __restrict__ bcomb) {
    int t = blockIdx.x * blockDim.x + threadIdx.x;
    if (t < 64 * NCLS) {
        int f = t / NCLS, c = t % NCLS;
        float acc = 0.f;
        for (int k = 0; k < 128; ++k) acc += W2[f * 128 + k] * Wfc[k * NCLS + c];
        wcomb[t] = acc;
    } else if (t < 64 * NCLS + NCLS) {
        int c = t - 64 * NCLS;
        float acc = bfc[c];
        for (int k = 0; k < 128; ++k) acc += b2[k] * Wfc[k * NCLS + c];
        bcomb[c] = acc;
    }
}

// S6: conv1 per graph — LDS fp32 accumulation of a1 = u[self] + sum u[src];
//     write packed zp[i] = { half2(dinv*a1), fp32 dinv }. 4 graphs/block.
__global__ void conv1_k(const int* __restrict__ pe, const int* __restrict__ eoff,
                        const int* __restrict__ ecnt, const unsigned int* __restrict__ up,
                        const float* __restrict__ dinv, uint2* __restrict__ zp) {
    __shared__ float a1loc[4][NPG][2];
    int lane = threadIdx.x & 63, wv = threadIdx.x >> 6;
    int g    = blockIdx.x * 4 + wv;
    int base = g * NPG;
    if (lane < 2 * NPG) {                       // self-loop init
        int n = lane >> 1, c = lane & 1;
        unsigned int raw = up[base + n];
        __half2 h = *reinterpret_cast<__half2*>(&raw);
        float2 uv = __half22float2(h);
        a1loc[wv][n][c] = c ? uv.y : uv.x;
    }
    __syncthreads();
    int off = eoff[g], cg = ecnt[g];
    for (int i = lane; i < cg; i += 64) {       // per-lane random gather (high MLP)
        int p = pe[off + i];
        unsigned int raw = up[p >> 5];
        __half2 h = *reinterpret_cast<__half2*>(&raw);
        float2 uv = __half22float2(h);
        atomicAdd(&a1loc[wv][p & 31][0], uv.x);
        atomicAdd(&a1loc[wv][p & 31][1], uv.y);
    }
    __syncthreads();
    if (lane < NPG) {
        float dv = dinv[base + lane];
        __half2 h = __floats2half2_rn(dv * a1loc[wv][lane][0],
                                      dv * a1loc[wv][lane][1]);
        uint2 w;
        w.x = *reinterpret_cast<unsigned int*>(&h);
        w.y = __float_as_uint(dv);
        zp[base + lane] = w;
    }
}

// S7: conv2 + mean-pool + FC + log_softmax fused. ONE wave per graph, 4/block.
// Phase A: per-lane gather of all edge+self records into LDS (one latency round,
//          up to 64 independent cachelines per load instruction).
// Phase B: broadcast-consume from LDS (no memory latency), FC + softmax.
__global__ void conv2pool_k(const int* __restrict__ pe, const int* __restrict__ eoff,
                            const int* __restrict__ ecnt, const uint2* __restrict__ zp,
                            const float* __restrict__ dinv,
                            const float* __restrict__ W1, const float* __restrict__ b1,
                            const float* __restrict__ wcomb, const float* __restrict__ bcomb,
                            float* __restrict__ out) {
    __shared__ uint2 rec[4][REC_MAX];
    __shared__ float ps[4][64];
    int lane = threadIdx.x & 63, wv = threadIdx.x >> 6;
    int g    = blockIdx.x * 4 + wv;
    int base = g * NPG;
    int off  = eoff[g];
    int cg   = ecnt[g];
    if (cg > REC_MAX - NPG) cg = REC_MAX - NPG;   // safety clamp (statistically unreachable)

    // Phase A: build records {half2 z_src, fp32 coef}
    for (int i = lane; i < cg; i += 64) {
        int p = pe[off + i];
        uint2 w = zp[p >> 5];                     // per-lane random 8B gather
        float ds = __uint_as_float(w.y);
        float dd = dinv[base + (p & 31)];         // graph-local, cache-hot
        w.y = __float_as_uint(ds * dd);
        rec[wv][i] = w;
    }
    if (lane < NPG) {                             // self records, coef = dinv^2
        uint2 w = zp[base + lane];
        float dv = __uint_as_float(w.y);
        w.y = __float_as_uint(dv * dv);
        rec[wv][cg + lane] = w;
    }
    __syncthreads();

    // Phase B: streaming consume from LDS
    float w0 = W1[lane], w1 = W1[64 + lane], bb = b1[lane];
    float acc = 0.f;
    int nrec = cg + NPG;
    #pragma unroll 4
    for (int r = 0; r < nrec; ++r) {
        uint2 w = rec[wv][r];
        __half2 hz = *reinterpret_cast<__half2*>(&w.x);
        float2 z = __half22float2(hz);
        acc += __uint_as_float(w.y) * fmaxf(z.x * w0 + z.y * w1 + bb, 0.0f);
    }
    ps[wv][lane] = acc * (1.0f / (float)NPG);
    __syncthreads();

    // FC + log_softmax (per wave, on its own graph)
    float logit = 0.f;
    if (lane < NCLS) {
        logit = bcomb[lane];
        #pragma unroll
        for (int f = 0; f < 64; ++f) logit += ps[wv][f] * wcomb[f * NCLS + lane];
    }
    float m = (lane < NCLS) ? logit : -INFINITY;
    #pragma unroll
    for (int o = 32; o; o >>= 1) m = fmaxf(m, __shfl_xor(m, o, 64));
    float ex = (lane < NCLS) ? expf(logit - m) : 0.f;
    float s = ex;
    #pragma unroll
    for (int o = 32; o; o >>= 1) s += __shfl_xor(s, o, 64);
    if (lane < NCLS) out[g * NCLS + lane] = logit - m - logf(s);
}

// ---------------------------------------------------------------------------
extern "C" void kernel_launch(void* const* d_in, const int* in_sizes, int n_in,
                              void* d_out, int out_size, void* d_ws, size_t ws_size,
                              hipStream_t stream) {
    const float* x   = (const float*)d_in[0];
    const int*   src = (const int*)  d_in[1];
    const int*   dst = (const int*)  d_in[2];
    // d_in[3] = batch (unused; batch == i/21 by construction)
    const float* W1  = (const float*)d_in[4];
    const float* b1  = (const float*)d_in[5];
    const float* W2  = (const float*)d_in[6];
    const float* b2  = (const float*)d_in[7];
    const float* Wfc = (const float*)d_in[8];
    const float* bfc = (const float*)d_in[9];
    float* out = (float*)d_out;

    // workspace carve-up (256B aligned) — total ~34 MB
    char* ws = (char*)d_ws;
    size_t off = 0;
    auto carve = [&](size_t bytes) { char* p = ws + off; off += (bytes + 255) & ~(size_t)255; return p; };
    int*          cnt   = (int*)          carve((size_t)NODES * 4);    //  4.2 MB
    int*          ecnt  = (int*)          carve((size_t)GRAPHS * 4);   //  0.2 MB
    int*          eoff  = (int*)          carve((size_t)GRAPHS * 4);   //  0.2 MB
    int*          ecur  = (int*)          carve((size_t)GRAPHS * 4);   //  0.2 MB
    int*          btot  = (int*)          carve((size_t)NCHUNK * 4);
    float*        dinv  = (float*)        carve((size_t)NODES * 4);    //  4.2 MB
    unsigned int* up    = (unsigned int*) carve((size_t)NODES * 4);    //  4.2 MB
    uint2*        zp    = (uint2*)        carve((size_t)NODES * 8);    //  8.4 MB
    int*          pe    = (int*)          carve((size_t)EDGES * 4);    //  8.4 MB
    float*        wcomb = (float*)        carve((size_t)64 * NCLS * 4);
    float*        bcomb = (float*)        carve((size_t)NCLS * 4);
    (void)ws_size;

    hipMemsetAsync(cnt,  0, (size_t)NODES * 4, stream);
    hipMemsetAsync(ecur, 0, (size_t)GRAPHS * 4, stream);

    count_k    <<<(EDGES + 255) / 256, 256, 0, stream>>>(dst, cnt);
    scan1_k    <<<NCHUNK, 1024, 0, stream>>>(cnt, ecnt, eoff, btot);
    scan2_k    <<<NCHUNK, 1024, 0, stream>>>(btot, eoff);
    scatter_k  <<<(EDGES + 255) / 256, 256, 0, stream>>>(src, dst, eoff, ecur, pe);
    init_nodes <<<(NODES + 255) / 256, 256, 0, stream>>>(x, cnt, dinv, up);
    make_wcomb <<<(64 * NCLS + NCLS + 255) / 256, 256, 0, stream>>>(W2, b2, Wfc, bfc, wcomb, bcomb);
    conv1_k    <<<GRAPHS / 4, 256, 0, stream>>>(pe, eoff, ecnt, up, dinv, zp);
    conv2pool_k<<<GRAPHS / 4, 256, 0, stream>>>(pe, eoff, ecnt, zp, dinv, W1, b1, wcomb, bcomb, out);
}

// Round 8
// 193.045 us; speedup vs baseline: 4.2363x; 1.7589x over previous
//
#include <hip/hip_runtime.h>
#include <hip/hip_fp16.h>
#include <math.h>

// Problem constants (from reference)
#define NODES   1050000
#define EDGES   2100000
#define GRAPHS  50000
#define NPG     21      // nodes per graph
#define NCLS    26
#define NCHUNK  ((GRAPHS + 1023) / 1024)   // 49 scan chunks
#define REC_MAX 168     // per-graph record cap in conv2pool (cg<=147 stat + 21 self)

// Bucket sort geometry
#define NBUCK   1024
#define GPB     49      // graphs per bucket (1024*49 = 50176 >= 50000)
#define BCAP    2816    // records per bucket cap (E[2058], sigma~45 -> z>16)
#define NBLK_A  128     // blocks for bucket_k
#define EPB     ((EDGES + NBLK_A - 1) / NBLK_A)   // 16407 edges per block

// ---------------------------------------------------------------------------
// S1: bucket scatter with per-block chunk allocation (full-cacheline writes).
// Record: s(21b) << 11 | g_local(6b) << 5 | dloc(5b)   [unsigned!]
__global__ void __launch_bounds__(256) bucket_k(const int* __restrict__ src,
                                                const int* __restrict__ dst,
                                                int* __restrict__ bcnt,
                                                unsigned int* __restrict__ arena) {
    __shared__ int hist[NBUCK];
    __shared__ int gbase[NBUCK];
    int tid = threadIdx.x;
    for (int b = tid; b < NBUCK; b += 256) hist[b] = 0;
    __syncthreads();
    int e0 = blockIdx.x * EPB;
    int e1 = e0 + EPB; if (e1 > EDGES) e1 = EDGES;
    // phase 1: per-block histogram over buckets
    for (int e = e0 + tid; e < e1; e += 256) {
        int g = dst[e] / NPG;
        atomicAdd(&hist[g / GPB], 1);
    }
    __syncthreads();
    // phase 2: one global chunk allocation per (block,bucket)
    for (int b = tid; b < NBUCK; b += 256) {
        int h = hist[b];
        gbase[b] = h ? atomicAdd(&bcnt[b], h) : 0;
        hist[b] = 0;                      // reuse as run counter
    }
    __syncthreads();
    // phase 3: place records into the block's contiguous chunks
    for (int e = e0 + tid; e < e1; e += 256) {
        int s = src[e], d = dst[e];
        int g = d / NPG;
        int b = g / GPB;
        int r = atomicAdd(&hist[b], 1);
        int pos = gbase[b] + r;
        if (pos < BCAP)
            arena[(size_t)b * BCAP + pos] =
                ((unsigned int)s << 11) | ((unsigned int)(g - b * GPB) << 5)
                | (unsigned int)(d - g * NPG);
    }
}

// S2: per-bucket node histogram -> per-node in-degree cnt + per-graph ecnt.
// Sequential writes, no global atomics (replaces old count_k).
__global__ void __launch_bounds__(256) hist_k(const int* __restrict__ bcnt,
                                              const unsigned int* __restrict__ arena,
                                              int* __restrict__ cnt,
                                              int* __restrict__ ecnt) {
    __shared__ int h[GPB * NPG];          // 1029 node counters
    int b = blockIdx.x, tid = threadIdx.x;
    for (int i = tid; i < GPB * NPG; i += 256) h[i] = 0;
    __syncthreads();
    int n = bcnt[b]; if (n > BCAP) n = BCAP;
    const unsigned int* ar = arena + (size_t)b * BCAP;
    for (int i = tid; i < n; i += 256) {
        unsigned int rec = ar[i];
        atomicAdd(&h[((rec >> 5) & 63) * NPG + (rec & 31)], 1);
    }
    __syncthreads();
    int node0 = b * GPB * NPG;            // node id of bucket's first node
    for (int i = tid; i < GPB * NPG; i += 256) {
        int node = node0 + i;
        if (node < NODES) cnt[node] = h[i];
    }
    int g0 = b * GPB;
    for (int gl = tid; gl < GPB; gl += 256) {
        int g = g0 + gl;
        if (g < GRAPHS) {
            int s = 0;
            #pragma unroll
            for (int k = 0; k < NPG; ++k) s += h[gl * NPG + k];
            ecnt[g] = s;
        }
    }
}

// S3a: chunk-local exclusive scan of ecnt
__global__ void scan1_k(const int* __restrict__ ecnt, int* __restrict__ eoff,
                        int* __restrict__ btot) {
    __shared__ int tmp[1024];
    int g = blockIdx.x * 1024 + threadIdx.x;
    int v = (g < GRAPHS) ? ecnt[g] : 0;
    tmp[threadIdx.x] = v;
    __syncthreads();
    for (int off = 1; off < 1024; off <<= 1) {
        int t = (threadIdx.x >= off) ? tmp[threadIdx.x - off] : 0;
        __syncthreads();
        tmp[threadIdx.x] += t;
        __syncthreads();
    }
    if (g < GRAPHS) eoff[g] = tmp[threadIdx.x] - v;   // exclusive
    if (threadIdx.x == 1023) btot[blockIdx.x] = tmp[1023];
}

// S3b: add chunk-total prefix
__global__ void scan2_k(const int* __restrict__ btot, int* __restrict__ eoff) {
    int pre = 0;
    for (int j = 0; j < (int)blockIdx.x; ++j) pre += btot[j];
    int i = blockIdx.x * 1024 + threadIdx.x;
    if (i < GRAPHS) eoff[i] += pre;
}

// S4: per-bucket placement into final graph-sorted pe (s<<5 | dloc).
// Each bucket's pe window is contiguous (~8KB) -> L2-local full-line writes.
__global__ void __launch_bounds__(256) place_k(const int* __restrict__ bcnt,
                                               const unsigned int* __restrict__ arena,
                                               const int* __restrict__ eoff,
                                               int* __restrict__ pe) {
    __shared__ int go[GPB];
    int b = blockIdx.x, tid = threadIdx.x;
    int g0 = b * GPB;
    if (tid < GPB) {
        int g = g0 + tid;
        go[tid] = (g < GRAPHS) ? eoff[g] : 0;
    }
    __syncthreads();
    int n = bcnt[b]; if (n > BCAP) n = BCAP;
    const unsigned int* ar = arena + (size_t)b * BCAP;
    for (int i = tid; i < n; i += 256) {
        unsigned int rec = ar[i];
        int pos = atomicAdd(&go[(rec >> 5) & 63], 1);
        pe[pos] = (int)(((rec >> 11) << 5) | (rec & 31));
    }
}

// S5: dinv = rsqrt(deg+1); u packed = half2(dinv*x) (4 B per node)
__global__ void init_nodes(const float* __restrict__ x, const int* __restrict__ cnt,
                           float* __restrict__ dinv, unsigned int* __restrict__ up) {
    int i = blockIdx.x * blockDim.x + threadIdx.x;
    if (i < NODES) {
        float d = 1.0f / sqrtf((float)(cnt[i] + 1));
        dinv[i] = d;
        float2 xv = ((const float2*)x)[i];
        __half2 h = __floats2half2_rn(d * xv.x, d * xv.y);
        up[i] = *reinterpret_cast<unsigned int*>(&h);
    }
}

// S6 (tiny): wcomb = W2@Wfc [64,26]; bcomb = b2@Wfc + bfc [26]
__global__ void make_wcomb(const float* __restrict__ W2, const float* __restrict__ b2,
                           const float* __restrict__ Wfc, const float* __restrict__ bfc,
                           float* __restrict__ wcomb, float* __restrict__ bcomb) {
    int t = blockIdx.x * blockDim.x + threadIdx.x;
    if (t < 64 * NCLS) {
        int f = t / NCLS, c = t % NCLS;
        float acc = 0.f;
        for (int k = 0; k < 128; ++k) acc += W2[f * 128 + k] * Wfc[k * NCLS + c];
        wcomb[t] = acc;
    } else if (t < 64 * NCLS + NCLS) {
        int c = t - 64 * NCLS;
        float acc = bfc[c];
        for (int k = 0; k < 128; ++k) acc += b2[k] * Wfc[k * NCLS + c];
        bcomb[c] = acc;
    }
}

// S7: conv1 per graph — LDS fp32 accumulation of a1 = u[self] + sum u[src];
//     write packed zp[i] = { half2(dinv*a1), fp32 dinv }. 4 graphs/block.
__global__ void conv1_k(const int* __restrict__ pe, const int* __restrict__ eoff,
                        const int* __restrict__ ecnt, const unsigned int* __restrict__ up,
                        const float* __restrict__ dinv, uint2* __restrict__ zp) {
    __shared__ float a1loc[4][NPG][2];
    int lane = threadIdx.x & 63, wv = threadIdx.x >> 6;
    int g    = blockIdx.x * 4 + wv;
    int base = g * NPG;
    if (lane < 2 * NPG) {                       // self-loop init
        int n = lane >> 1, c = lane & 1;
        unsigned int raw = up[base + n];
        __half2 h = *reinterpret_cast<__half2*>(&raw);
        float2 uv = __half22float2(h);
        a1loc[wv][n][c] = c ? uv.y : uv.x;
    }
    __syncthreads();
    int off = eoff[g], cg = ecnt[g];
    for (int i = lane; i < cg; i += 64) {       // per-lane random gather (high MLP)
        int p = pe[off + i];
        unsigned int raw = up[p >> 5];
        __half2 h = *reinterpret_cast<__half2*>(&raw);
        float2 uv = __half22float2(h);
        atomicAdd(&a1loc[wv][p & 31][0], uv.x);
        atomicAdd(&a1loc[wv][p & 31][1], uv.y);
    }
    __syncthreads();
    if (lane < NPG) {
        float dv = dinv[base + lane];
        __half2 h = __floats2half2_rn(dv * a1loc[wv][lane][0],
                                      dv * a1loc[wv][lane][1]);
        uint2 w;
        w.x = *reinterpret_cast<unsigned int*>(&h);
        w.y = __float_as_uint(dv);
        zp[base + lane] = w;
    }
}

// S8: conv2 + mean-pool + FC + log_softmax fused. ONE wave per graph, 4/block.
// Phase A: per-lane gather of all edge+self records into LDS.
// Phase B: broadcast-consume from LDS, FC + softmax.
__global__ void conv2pool_k(const int* __restrict__ pe, const int* __restrict__ eoff,
                            const int* __restrict__ ecnt, const uint2* __restrict__ zp,
                            const float* __restrict__ dinv,
                            const float* __restrict__ W1, const float* __restrict__ b1,
                            const float* __restrict__ wcomb, const float* __restrict__ bcomb,
                            float* __restrict__ out) {
    __shared__ uint2 rec[4][REC_MAX];
    __shared__ float ps[4][64];
    int lane = threadIdx.x & 63, wv = threadIdx.x >> 6;
    int g    = blockIdx.x * 4 + wv;
    int base = g * NPG;
    int off  = eoff[g];
    int cg   = ecnt[g];
    if (cg > REC_MAX - NPG) cg = REC_MAX - NPG;   // safety clamp

    for (int i = lane; i < cg; i += 64) {
        int p = pe[off + i];
        uint2 w = zp[p >> 5];                     // per-lane random 8B gather
        float ds = __uint_as_float(w.y);
        float dd = dinv[base + (p & 31)];         // graph-local, cache-hot
        w.y = __float_as_uint(ds * dd);
        rec[wv][i] = w;
    }
    if (lane < NPG) {                             // self records, coef = dinv^2
        uint2 w = zp[base + lane];
        float dv = __uint_as_float(w.y);
        w.y = __float_as_uint(dv * dv);
        rec[wv][cg + lane] = w;
    }
    __syncthreads();

    float w0 = W1[lane], w1 = W1[64 + lane], bb = b1[lane];
    float acc = 0.f;
    int nrec = cg + NPG;
    #pragma unroll 4
    for (int r = 0; r < nrec; ++r) {
        uint2 w = rec[wv][r];
        __half2 hz = *reinterpret_cast<__half2*>(&w.x);
        float2 z = __half22float2(hz);
        acc += __uint_as_float(w.y) * fmaxf(z.x * w0 + z.y * w1 + bb, 0.0f);
    }
    ps[wv][lane] = acc * (1.0f / (float)NPG);
    __syncthreads();

    float logit = 0.f;
    if (lane < NCLS) {
        logit = bcomb[lane];
        #pragma unroll
        for (int f = 0; f < 64; ++f) logit += ps[wv][f] * wcomb[f * NCLS + lane];
    }
    float m = (lane < NCLS) ? logit : -INFINITY;
    #pragma unroll
    for (int o = 32; o; o >>= 1) m = fmaxf(m, __shfl_xor(m, o, 64));
    float ex = (lane < NCLS) ? expf(logit - m) : 0.f;
    float s = ex;
    #pragma unroll
    for (int o = 32; o; o >>= 1) s += __shfl_xor(s, o, 64);
    if (lane < NCLS) out[g * NCLS + lane] = logit - m - logf(s);
}

// ---------------------------------------------------------------------------
extern "C" void kernel_launch(void* const* d_in, const int* in_sizes, int n_in,
                              void* d_out, int out_size, void* d_ws, size_t ws_size,
                              hipStream_t stream) {
    const float* x   = (const float*)d_in[0];
    const int*   src = (const int*)  d_in[1];
    const int*   dst = (const int*)  d_in[2];
    // d_in[3] = batch (unused; batch == i/21 by construction)
    const float* W1  = (const float*)d_in[4];
    const float* b1  = (const float*)d_in[5];
    const float* W2  = (const float*)d_in[6];
    const float* b2  = (const float*)d_in[7];
    const float* Wfc = (const float*)d_in[8];
    const float* bfc = (const float*)d_in[9];
    float* out = (float*)d_out;

    // workspace carve-up (256B aligned) — total ~41.5 MB
    char* ws = (char*)d_ws;
    size_t off = 0;
    auto carve = [&](size_t bytes) { char* p = ws + off; off += (bytes + 255) & ~(size_t)255; return p; };
    int*          cnt   = (int*)          carve((size_t)NODES * 4);          //  4.2 MB
    int*          ecnt  = (int*)          carve((size_t)GRAPHS * 4);         //  0.2 MB
    int*          eoff  = (int*)          carve((size_t)GRAPHS * 4);         //  0.2 MB
    int*          btot  = (int*)          carve((size_t)NCHUNK * 4);
    int*          bcnt  = (int*)          carve((size_t)NBUCK * 4);
    float*        dinv  = (float*)        carve((size_t)NODES * 4);          //  4.2 MB
    unsigned int* up    = (unsigned int*) carve((size_t)NODES * 4);          //  4.2 MB
    uint2*        zp    = (uint2*)        carve((size_t)NODES * 8);          //  8.4 MB
    int*          pe    = (int*)          carve((size_t)EDGES * 4);          //  8.4 MB
    unsigned int* arena = (unsigned int*) carve((size_t)NBUCK * BCAP * 4);   // 11.5 MB
    float*        wcomb = (float*)        carve((size_t)64 * NCLS * 4);
    float*        bcomb = (float*)        carve((size_t)NCLS * 4);
    (void)ws_size;

    hipMemsetAsync(bcnt, 0, (size_t)NBUCK * 4, stream);

    bucket_k   <<<NBLK_A, 256, 0, stream>>>(src, dst, bcnt, arena);
    hist_k     <<<NBUCK, 256, 0, stream>>>(bcnt, arena, cnt, ecnt);
    scan1_k    <<<NCHUNK, 1024, 0, stream>>>(ecnt, eoff, btot);
    scan2_k    <<<NCHUNK, 1024, 0, stream>>>(btot, eoff);
    place_k    <<<NBUCK, 256, 0, stream>>>(bcnt, arena, eoff, pe);
    init_nodes <<<(NODES + 255) / 256, 256, 0, stream>>>(x, cnt, dinv, up);
    make_wcomb <<<(64 * NCLS + NCLS + 255) / 256, 256, 0, stream>>>(W2, b2, Wfc, bfc, wcomb, bcomb);
    conv1_k    <<<GRAPHS / 4, 256, 0, stream>>>(pe, eoff, ecnt, up, dinv, zp);
    conv2pool_k<<<GRAPHS / 4, 256, 0, stream>>>(pe, eoff, ecnt, zp, dinv, W1, b1, wcomb, bcomb, out);
}

// Round 9
// 155.455 us; speedup vs baseline: 5.2606x; 1.2418x over previous
//
#include <hip/hip_runtime.h>
#include <hip/hip_fp16.h>
#include <math.h>

// Problem constants (from reference)
#define NODES   1050000
#define EDGES   2100000
#define GRAPHS  50000
#define NPG     21      // nodes per graph
#define NCLS    26
#define NCHUNK  ((GRAPHS + 1023) / 1024)   // 49 scan chunks
#define REC_MAX 168     // per-graph record cap in conv2pool (cg<=147 stat + 21 self)

// Bucket sort geometry
#define NBUCK   1024
#define GPB     49      // graphs per bucket (1024*49 = 50176 >= 50000)
#define BCAP    2816    // records per bucket cap (E[2051], sigma~45 -> +17 sigma)
#define NBLK_A  256     // blocks for bucket_k
#define NTHR_A  1024    // threads for bucket_k (16 waves/CU at 1 block/CU)
#define EPB     ((EDGES + NBLK_A - 1) / NBLK_A)   // 8204 edges per block

// ---------------------------------------------------------------------------
// S1: bucket scatter with per-block chunk allocation (near-full-line writes).
// Record: s(21b) << 11 | g_local(6b) << 5 | dloc(5b)   [unsigned!]
__global__ void __launch_bounds__(NTHR_A) bucket_k(const int* __restrict__ src,
                                                   const int* __restrict__ dst,
                                                   int* __restrict__ bcnt,
                                                   unsigned int* __restrict__ arena) {
    __shared__ int hist[NBUCK];
    __shared__ int gbase[NBUCK];
    int tid = threadIdx.x;
    for (int b = tid; b < NBUCK; b += NTHR_A) hist[b] = 0;
    __syncthreads();
    int e0 = blockIdx.x * EPB;
    int e1 = e0 + EPB; if (e1 > EDGES) e1 = EDGES;
    // phase 1: per-block histogram over buckets
    for (int e = e0 + tid; e < e1; e += NTHR_A) {
        int g = dst[e] / NPG;
        atomicAdd(&hist[g / GPB], 1);
    }
    __syncthreads();
    // phase 2: one global chunk allocation per (block,bucket)
    for (int b = tid; b < NBUCK; b += NTHR_A) {
        int h = hist[b];
        gbase[b] = h ? atomicAdd(&bcnt[b], h) : 0;
        hist[b] = 0;                      // reuse as run counter
    }
    __syncthreads();
    // phase 3: place records into the block's contiguous chunks
    for (int e = e0 + tid; e < e1; e += NTHR_A) {
        int s = src[e], d = dst[e];
        int g = d / NPG;
        int b = g / GPB;
        int r = atomicAdd(&hist[b], 1);
        int pos = gbase[b] + r;
        if (pos < BCAP)
            arena[(size_t)b * BCAP + pos] =
                ((unsigned int)s << 11) | ((unsigned int)(g - b * GPB) << 5)
                | (unsigned int)(d - g * NPG);
    }
}

// S2: per-bucket node histogram -> per-node in-degree cnt + per-graph ecnt.
// Sequential writes, no global atomics.
__global__ void __launch_bounds__(256) hist_k(const int* __restrict__ bcnt,
                                              const unsigned int* __restrict__ arena,
                                              int* __restrict__ cnt,
                                              int* __restrict__ ecnt) {
    __shared__ int h[GPB * NPG];          // 1029 node counters
    int b = blockIdx.x, tid = threadIdx.x;
    for (int i = tid; i < GPB * NPG; i += 256) h[i] = 0;
    __syncthreads();
    int n = bcnt[b]; if (n > BCAP) n = BCAP;
    const unsigned int* ar = arena + (size_t)b * BCAP;
    for (int i = tid; i < n; i += 256) {
        unsigned int rec = ar[i];
        atomicAdd(&h[((rec >> 5) & 63) * NPG + (rec & 31)], 1);
    }
    __syncthreads();
    int node0 = b * GPB * NPG;            // node id of bucket's first node
    for (int i = tid; i < GPB * NPG; i += 256) {
        int node = node0 + i;
        if (node < NODES) cnt[node] = h[i];
    }
    int g0 = b * GPB;
    for (int gl = tid; gl < GPB; gl += 256) {
        int g = g0 + gl;
        if (g < GRAPHS) {
            int s = 0;
            #pragma unroll
            for (int k = 0; k < NPG; ++k) s += h[gl * NPG + k];
            ecnt[g] = s;
        }
    }
}

// S3a: chunk-local exclusive scan of ecnt
__global__ void scan1_k(const int* __restrict__ ecnt, int* __restrict__ eoff,
                        int* __restrict__ btot) {
    __shared__ int tmp[1024];
    int g = blockIdx.x * 1024 + threadIdx.x;
    int v = (g < GRAPHS) ? ecnt[g] : 0;
    tmp[threadIdx.x] = v;
    __syncthreads();
    for (int off = 1; off < 1024; off <<= 1) {
        int t = (threadIdx.x >= off) ? tmp[threadIdx.x - off] : 0;
        __syncthreads();
        tmp[threadIdx.x] += t;
        __syncthreads();
    }
    if (g < GRAPHS) eoff[g] = tmp[threadIdx.x] - v;   // exclusive
    if (threadIdx.x == 1023) btot[blockIdx.x] = tmp[1023];
}

// S3b: add chunk-total prefix
__global__ void scan2_k(const int* __restrict__ btot, int* __restrict__ eoff) {
    int pre = 0;
    for (int j = 0; j < (int)blockIdx.x; ++j) pre += btot[j];
    int i = blockIdx.x * 1024 + threadIdx.x;
    if (i < GRAPHS) eoff[i] += pre;
}

// S4: per-bucket placement into final graph-sorted pe (s<<5 | dloc).
__global__ void __launch_bounds__(256) place_k(const int* __restrict__ bcnt,
                                               const unsigned int* __restrict__ arena,
                                               const int* __restrict__ eoff,
                                               int* __restrict__ pe) {
    __shared__ int go[GPB];
    int b = blockIdx.x, tid = threadIdx.x;
    int g0 = b * GPB;
    if (tid < GPB) {
        int g = g0 + tid;
        go[tid] = (g < GRAPHS) ? eoff[g] : 0;
    }
    __syncthreads();
    int n = bcnt[b]; if (n > BCAP) n = BCAP;
    const unsigned int* ar = arena + (size_t)b * BCAP;
    for (int i = tid; i < n; i += 256) {
        unsigned int rec = ar[i];
        int pos = atomicAdd(&go[(rec >> 5) & 63], 1);
        pe[pos] = (int)(((rec >> 11) << 5) | (rec & 31));
    }
}

// S5: dinv = rsqrt(deg+1); u packed = half2(dinv*x) (4 B per node)
__global__ void init_nodes(const float* __restrict__ x, const int* __restrict__ cnt,
                           float* __restrict__ dinv, unsigned int* __restrict__ up) {
    int i = blockIdx.x * blockDim.x + threadIdx.x;
    if (i < NODES) {
        float d = 1.0f / sqrtf((float)(cnt[i] + 1));
        dinv[i] = d;
        float2 xv = ((const float2*)x)[i];
        __half2 h = __floats2half2_rn(d * xv.x, d * xv.y);
        up[i] = *reinterpret_cast<unsigned int*>(&h);
    }
}

// S6 (tiny): wcomb = W2@Wfc [64,26]; bcomb = b2@Wfc + bfc [26]
__global__ void make_wcomb(const float* __restrict__ W2, const float* __restrict__ b2,
                           const float* __restrict__ Wfc, const float* __restrict__ bfc,
                           float* __restrict__ wcomb, float* __restrict__ bcomb) {
    int t = blockIdx.x * blockDim.x + threadIdx.x;
    if (t < 64 * NCLS) {
        int f = t / NCLS, c = t % NCLS;
        float acc = 0.f;
        for (int k = 0; k < 128; ++k) acc += W2[f * 128 + k] * Wfc[k * NCLS + c];
        wcomb[t] = acc;
    } else if (t < 64 * NCLS + NCLS) {
        int c = t - 64 * NCLS;
        float acc = bfc[c];
        for (int k = 0; k < 128; ++k) acc += b2[k] * Wfc[k * NCLS + c];
        bcomb[c] = acc;
    }
}

// S7: conv1 per graph — LDS fp32 accumulation of a1 = u[self] + sum u[src];
//     write packed zp[i] = { half2(dinv*a1), fp32 dinv }. 4 graphs/block.
__global__ void conv1_k(const int* __restrict__ pe, const int* __restrict__ eoff,
                        const int* __restrict__ ecnt, const unsigned int* __restrict__ up,
                        const float* __restrict__ dinv, uint2* __restrict__ zp) {
    __shared__ float a1loc[4][NPG][2];
    int lane = threadIdx.x & 63, wv = threadIdx.x >> 6;
    int g    = blockIdx.x * 4 + wv;
    int base = g * NPG;
    if (lane < 2 * NPG) {                       // self-loop init
        int n = lane >> 1, c = lane & 1;
        unsigned int raw = up[base + n];
        __half2 h = *reinterpret_cast<__half2*>(&raw);
        float2 uv = __half22float2(h);
        a1loc[wv][n][c] = c ? uv.y : uv.x;
    }
    __syncthreads();
    int off = eoff[g], cg = ecnt[g];
    for (int i = lane; i < cg; i += 64) {       // per-lane random gather (high MLP)
        int p = pe[off + i];
        unsigned int raw = up[p >> 5];
        __half2 h = *reinterpret_cast<__half2*>(&raw);
        float2 uv = __half22float2(h);
        atomicAdd(&a1loc[wv][p & 31][0], uv.x);
        atomicAdd(&a1loc[wv][p & 31][1], uv.y);
    }
    __syncthreads();
    if (lane < NPG) {
        float dv = dinv[base + lane];
        __half2 h = __floats2half2_rn(dv * a1loc[wv][lane][0],
                                      dv * a1loc[wv][lane][1]);
        uint2 w;
        w.x = *reinterpret_cast<unsigned int*>(&h);
        w.y = __float_as_uint(dv);
        zp[base + lane] = w;
    }
}

// S8: conv2 + mean-pool + FC + log_softmax fused. ONE wave per graph, 4/block.
// Phase A: per-lane gather of all edge+self records into LDS.
// Phase B: broadcast-consume from LDS, FC + softmax.
__global__ void conv2pool_k(const int* __restrict__ pe, const int* __restrict__ eoff,
                            const int* __restrict__ ecnt, const uint2* __restrict__ zp,
                            const float* __restrict__ dinv,
                            const float* __restrict__ W1, const float* __restrict__ b1,
                            const float* __restrict__ wcomb, const float* __restrict__ bcomb,
                            float* __restrict__ out) {
    __shared__ uint2 rec[4][REC_MAX];
    __shared__ float ps[4][64];
    int lane = threadIdx.x & 63, wv = threadIdx.x >> 6;
    int g    = blockIdx.x * 4 + wv;
    int base = g * NPG;
    int off  = eoff[g];
    int cg   = ecnt[g];
    if (cg > REC_MAX - NPG) cg = REC_MAX - NPG;   // safety clamp

    for (int i = lane; i < cg; i += 64) {
        int p = pe[off + i];
        uint2 w = zp[p >> 5];                     // per-lane random 8B gather
        float ds = __uint_as_float(w.y);
        float dd = dinv[base + (p & 31)];         // graph-local, cache-hot
        w.y = __float_as_uint(ds * dd);
        rec[wv][i] = w;
    }
    if (lane < NPG) {                             // self records, coef = dinv^2
        uint2 w = zp[base + lane];
        float dv = __uint_as_float(w.y);
        w.y = __float_as_uint(dv * dv);
        rec[wv][cg + lane] = w;
    }
    __syncthreads();

    float w0 = W1[lane], w1 = W1[64 + lane], bb = b1[lane];
    float acc = 0.f;
    int nrec = cg + NPG;
    #pragma unroll 4
    for (int r = 0; r < nrec; ++r) {
        uint2 w = rec[wv][r];
        __half2 hz = *reinterpret_cast<__half2*>(&w.x);
        float2 z = __half22float2(hz);
        acc += __uint_as_float(w.y) * fmaxf(z.x * w0 + z.y * w1 + bb, 0.0f);
    }
    ps[wv][lane] = acc * (1.0f / (float)NPG);
    __syncthreads();

    float logit = 0.f;
    if (lane < NCLS) {
        logit = bcomb[lane];
        #pragma unroll
        for (int f = 0; f < 64; ++f) logit += ps[wv][f] * wcomb[f * NCLS + lane];
    }
    float m = (lane < NCLS) ? logit : -INFINITY;
    #pragma unroll
    for (int o = 32; o; o >>= 1) m = fmaxf(m, __shfl_xor(m, o, 64));
    float ex = (lane < NCLS) ? expf(logit - m) : 0.f;
    float s = ex;
    #pragma unroll
    for (int o = 32; o; o >>= 1) s += __shfl_xor(s, o, 64);
    if (lane < NCLS) out[g * NCLS + lane] = logit - m - logf(s);
}

// ---------------------------------------------------------------------------
extern "C" void kernel_launch(void* const* d_in, const int* in_sizes, int n_in,
                              void* d_out, int out_size, void* d_ws, size_t ws_size,
                              hipStream_t stream) {
    const float* x   = (const float*)d_in[0];
    const int*   src = (const int*)  d_in[1];
    const int*   dst = (const int*)  d_in[2];
    // d_in[3] = batch (unused; batch == i/21 by construction)
    const float* W1  = (const float*)d_in[4];
    const float* b1  = (const float*)d_in[5];
    const float* W2  = (const float*)d_in[6];
    const float* b2  = (const float*)d_in[7];
    const float* Wfc = (const float*)d_in[8];
    const float* bfc = (const float*)d_in[9];
    float* out = (float*)d_out;

    // workspace carve-up (256B aligned) — total ~41.5 MB
    char* ws = (char*)d_ws;
    size_t off = 0;
    auto carve = [&](size_t bytes) { char* p = ws + off; off += (bytes + 255) & ~(size_t)255; return p; };
    int*          cnt   = (int*)          carve((size_t)NODES * 4);          //  4.2 MB
    int*          ecnt  = (int*)          carve((size_t)GRAPHS * 4);         //  0.2 MB
    int*          eoff  = (int*)          carve((size_t)GRAPHS * 4);         //  0.2 MB
    int*          btot  = (int*)          carve((size_t)NCHUNK * 4);
    int*          bcnt  = (int*)          carve((size_t)NBUCK * 4);
    float*        dinv  = (float*)        carve((size_t)NODES * 4);          //  4.2 MB
    unsigned int* up    = (unsigned int*) carve((size_t)NODES * 4);          //  4.2 MB
    uint2*        zp    = (uint2*)        carve((size_t)NODES * 8);          //  8.4 MB
    int*          pe    = (int*)          carve((size_t)EDGES * 4);          //  8.4 MB
    unsigned int* arena = (unsigned int*) carve((size_t)NBUCK * BCAP * 4);   // 11.5 MB
    float*        wcomb = (float*)        carve((size_t)64 * NCLS * 4);
    float*        bcomb = (float*)        carve((size_t)NCLS * 4);
    (void)ws_size;

    hipMemsetAsync(bcnt, 0, (size_t)NBUCK * 4, stream);

    bucket_k   <<<NBLK_A, NTHR_A, 0, stream>>>(src, dst, bcnt, arena);
    hist_k     <<<NBUCK, 256, 0, stream>>>(bcnt, arena, cnt, ecnt);
    scan1_k    <<<NCHUNK, 1024, 0, stream>>>(ecnt, eoff, btot);
    scan2_k    <<<NCHUNK, 1024, 0, stream>>>(btot, eoff);
    place_k    <<<NBUCK, 256, 0, stream>>>(bcnt, arena, eoff, pe);
    init_nodes <<<(NODES + 255) / 256, 256, 0, stream>>>(x, cnt, dinv, up);
    make_wcomb <<<(64 * NCLS + NCLS + 255) / 256, 256, 0, stream>>>(W2, b2, Wfc, bfc, wcomb, bcomb);
    conv1_k    <<<GRAPHS / 4, 256, 0, stream>>>(pe, eoff, ecnt, up, dinv, zp);
    conv2pool_k<<<GRAPHS / 4, 256, 0, stream>>>(pe, eoff, ecnt, zp, dinv, W1, b1, wcomb, bcomb, out);
}

// Round 10
// 152.426 us; speedup vs baseline: 5.3652x; 1.0199x over previous
//
#include <hip/hip_runtime.h>
#include <hip/hip_fp16.h>
#include <math.h>

// Problem constants (from reference)
#define NODES   1050000
#define EDGES   2100000
#define GRAPHS  50000
#define NPG     21      // nodes per graph
#define NCLS    26
#define NCHUNK  ((GRAPHS + 1023) / 1024)   // 49 scan chunks
#define REC_MAX 168     // per-graph record cap in conv2pool (cg<=147 stat + 21 self)

// Bucket sort geometry
#define NBUCK   1024
#define GPB     49      // graphs per bucket (1024*49 = 50176 >= 50000)
#define BCAP    2816    // records per bucket cap (E[2051], sigma~45 -> +17 sigma)
#define NBLK_A  256     // blocks for bucket_k
#define NTHR_A  1024    // threads for bucket_k
#define EPB     ((EDGES + NBLK_A - 1) / NBLK_A)   // 8204 edges per block

// ---------------------------------------------------------------------------
// S1: bucket scatter with per-block chunk allocation (near-full-line writes).
// Record: s(21b) << 11 | g_local(6b) << 5 | dloc(5b)   [unsigned!]
__global__ void __launch_bounds__(NTHR_A) bucket_k(const int* __restrict__ src,
                                                   const int* __restrict__ dst,
                                                   int* __restrict__ bcnt,
                                                   unsigned int* __restrict__ arena) {
    __shared__ int hist[NBUCK];
    __shared__ int gbase[NBUCK];
    int tid = threadIdx.x;
    for (int b = tid; b < NBUCK; b += NTHR_A) hist[b] = 0;
    __syncthreads();
    int e0 = blockIdx.x * EPB;
    int e1 = e0 + EPB; if (e1 > EDGES) e1 = EDGES;
    for (int e = e0 + tid; e < e1; e += NTHR_A) {
        int g = dst[e] / NPG;
        atomicAdd(&hist[g / GPB], 1);
    }
    __syncthreads();
    for (int b = tid; b < NBUCK; b += NTHR_A) {
        int h = hist[b];
        gbase[b] = h ? atomicAdd(&bcnt[b], h) : 0;
        hist[b] = 0;                      // reuse as run counter
    }
    __syncthreads();
    for (int e = e0 + tid; e < e1; e += NTHR_A) {
        int s = src[e], d = dst[e];
        int g = d / NPG;
        int b = g / GPB;
        int r = atomicAdd(&hist[b], 1);
        int pos = gbase[b] + r;
        if (pos < BCAP)
            arena[(size_t)b * BCAP + pos] =
                ((unsigned int)s << 11) | ((unsigned int)(g - b * GPB) << 5)
                | (unsigned int)(d - g * NPG);
    }
}

// S2: per-bucket node histogram -> per-node in-degree cnt + per-graph ecnt.
__global__ void __launch_bounds__(256) hist_k(const int* __restrict__ bcnt,
                                              const unsigned int* __restrict__ arena,
                                              int* __restrict__ cnt,
                                              int* __restrict__ ecnt) {
    __shared__ int h[GPB * NPG];          // 1029 node counters
    int b = blockIdx.x, tid = threadIdx.x;
    for (int i = tid; i < GPB * NPG; i += 256) h[i] = 0;
    __syncthreads();
    int n = bcnt[b]; if (n > BCAP) n = BCAP;
    const unsigned int* ar = arena + (size_t)b * BCAP;
    for (int i = tid; i < n; i += 256) {
        unsigned int rec = ar[i];
        atomicAdd(&h[((rec >> 5) & 63) * NPG + (rec & 31)], 1);
    }
    __syncthreads();
    int node0 = b * GPB * NPG;
    for (int i = tid; i < GPB * NPG; i += 256) {
        int node = node0 + i;
        if (node < NODES) cnt[node] = h[i];
    }
    int g0 = b * GPB;
    for (int gl = tid; gl < GPB; gl += 256) {
        int g = g0 + gl;
        if (g < GRAPHS) {
            int s = 0;
            #pragma unroll
            for (int k = 0; k < NPG; ++k) s += h[gl * NPG + k];
            ecnt[g] = s;
        }
    }
}

// S3a: chunk-local exclusive scan of ecnt
__global__ void scan1_k(const int* __restrict__ ecnt, int* __restrict__ eoff,
                        int* __restrict__ btot) {
    __shared__ int tmp[1024];
    int g = blockIdx.x * 1024 + threadIdx.x;
    int v = (g < GRAPHS) ? ecnt[g] : 0;
    tmp[threadIdx.x] = v;
    __syncthreads();
    for (int off = 1; off < 1024; off <<= 1) {
        int t = (threadIdx.x >= off) ? tmp[threadIdx.x - off] : 0;
        __syncthreads();
        tmp[threadIdx.x] += t;
        __syncthreads();
    }
    if (g < GRAPHS) eoff[g] = tmp[threadIdx.x] - v;   // exclusive
    if (threadIdx.x == 1023) btot[blockIdx.x] = tmp[1023];
}

// S3b: add chunk-total prefix
__global__ void scan2_k(const int* __restrict__ btot, int* __restrict__ eoff) {
    int pre = 0;
    for (int j = 0; j < (int)blockIdx.x; ++j) pre += btot[j];
    int i = blockIdx.x * 1024 + threadIdx.x;
    if (i < GRAPHS) eoff[i] += pre;
}

// S4: per-bucket placement into final graph-sorted pe (s<<5 | dloc).
__global__ void __launch_bounds__(256) place_k(const int* __restrict__ bcnt,
                                               const unsigned int* __restrict__ arena,
                                               const int* __restrict__ eoff,
                                               int* __restrict__ pe) {
    __shared__ int go[GPB];
    int b = blockIdx.x, tid = threadIdx.x;
    int g0 = b * GPB;
    if (tid < GPB) {
        int g = g0 + tid;
        go[tid] = (g < GRAPHS) ? eoff[g] : 0;
    }
    __syncthreads();
    int n = bcnt[b]; if (n > BCAP) n = BCAP;
    const unsigned int* ar = arena + (size_t)b * BCAP;
    for (int i = tid; i < n; i += 256) {
        unsigned int rec = ar[i];
        int pos = atomicAdd(&go[(rec >> 5) & 63], 1);
        pe[pos] = (int)(((rec >> 11) << 5) | (rec & 31));
    }
}

// S5: dinv = rsqrt(deg+1); u packed = half2(dinv*x) (4 B per node)
__global__ void init_nodes(const float* __restrict__ x, const int* __restrict__ cnt,
                           float* __restrict__ dinv, unsigned int* __restrict__ up) {
    int i = blockIdx.x * blockDim.x + threadIdx.x;
    if (i < NODES) {
        float d = 1.0f / sqrtf((float)(cnt[i] + 1));
        dinv[i] = d;
        float2 xv = ((const float2*)x)[i];
        __half2 h = __floats2half2_rn(d * xv.x, d * xv.y);
        up[i] = *reinterpret_cast<unsigned int*>(&h);
    }
}

// S6 (tiny): wcomb = W2@Wfc [64,26]; bcomb = b2@Wfc + bfc [26]
__global__ void make_wcomb(const float* __restrict__ W2, const float* __restrict__ b2,
                           const float* __restrict__ Wfc, const float* __restrict__ bfc,
                           float* __restrict__ wcomb, float* __restrict__ bcomb) {
    int t = blockIdx.x * blockDim.x + threadIdx.x;
    if (t < 64 * NCLS) {
        int f = t / NCLS, c = t % NCLS;
        float acc = 0.f;
        for (int k = 0; k < 128; ++k) acc += W2[f * 128 + k] * Wfc[k * NCLS + c];
        wcomb[t] = acc;
    } else if (t < 64 * NCLS + NCLS) {
        int c = t - 64 * NCLS;
        float acc = bfc[c];
        for (int k = 0; k < 128; ++k) acc += b2[k] * Wfc[k * NCLS + c];
        bcomb[c] = acc;
    }
}

// S7: conv1 per graph — LDS fp32 accumulation of a1 = u[self] + sum u[src];
//     write packed zp[i] = { half2(dinv*a1), fp32 dinv }. 4 graphs/block.
__global__ void conv1_k(const int* __restrict__ pe, const int* __restrict__ eoff,
                        const int* __restrict__ ecnt, const unsigned int* __restrict__ up,
                        const float* __restrict__ dinv, uint2* __restrict__ zp) {
    __shared__ float a1loc[4][NPG][2];
    int lane = threadIdx.x & 63, wv = threadIdx.x >> 6;
    int g    = blockIdx.x * 4 + wv;
    int base = g * NPG;
    if (lane < 2 * NPG) {                       // self-loop init
        int n = lane >> 1, c = lane & 1;
        unsigned int raw = up[base + n];
        __half2 h = *reinterpret_cast<__half2*>(&raw);
        float2 uv = __half22float2(h);
        a1loc[wv][n][c] = c ? uv.y : uv.x;
    }
    __syncthreads();
    int off = eoff[g], cg = ecnt[g];
    for (int i = lane; i < cg; i += 64) {       // per-lane random gather (high MLP)
        int p = pe[off + i];
        unsigned int raw = up[p >> 5];
        __half2 h = *reinterpret_cast<__half2*>(&raw);
        float2 uv = __half22float2(h);
        atomicAdd(&a1loc[wv][p & 31][0], uv.x);
        atomicAdd(&a1loc[wv][p & 31][1], uv.y);
    }
    __syncthreads();
    if (lane < NPG) {
        float dv = dinv[base + lane];
        __half2 h = __floats2half2_rn(dv * a1loc[wv][lane][0],
                                      dv * a1loc[wv][lane][1]);
        uint2 w;
        w.x = *reinterpret_cast<unsigned int*>(&h);
        w.y = __float_as_uint(dv);
        zp[base + lane] = w;
    }
}

// S8: conv2 + mean-pool + FC + log_softmax fused. ONE wave per graph, 4/block.
// Phase A: per-lane gather; convert ONCE; store SoA fp32 {zx, zy, coef} in LDS.
// Phase B: 4 records per ds_read_b128 triple, pure fma/max stream.
__global__ void conv2pool_k(const int* __restrict__ pe, const int* __restrict__ eoff,
                            const int* __restrict__ ecnt, const uint2* __restrict__ zp,
                            const float* __restrict__ dinv,
                            const float* __restrict__ W1, const float* __restrict__ b1,
                            const float* __restrict__ wcomb, const float* __restrict__ bcomb,
                            float* __restrict__ out) {
    __shared__ float zxl[4][REC_MAX];     // 672 B rows, 16B-aligned
    __shared__ float zyl[4][REC_MAX];
    __shared__ float cfl[4][REC_MAX];
    __shared__ float ps[4][64];
    int lane = threadIdx.x & 63, wv = threadIdx.x >> 6;
    int g    = blockIdx.x * 4 + wv;
    int base = g * NPG;
    int off  = eoff[g];
    int cg   = ecnt[g];
    if (cg > REC_MAX - NPG) cg = REC_MAX - NPG;   // safety clamp

    for (int i = lane; i < cg; i += 64) {
        int p = pe[off + i];
        uint2 w = zp[p >> 5];                     // per-lane random 8B gather
        __half2 hz = *reinterpret_cast<__half2*>(&w.x);
        float2 z = __half22float2(hz);
        float ds = __uint_as_float(w.y);
        float dd = dinv[base + (p & 31)];         // graph-local, cache-hot
        zxl[wv][i] = z.x;
        zyl[wv][i] = z.y;
        cfl[wv][i] = ds * dd;
    }
    int nrec  = cg + NPG;
    int nrec4 = (nrec + 3) & ~3;
    if (lane < NPG) {                             // self records, coef = dinv^2
        uint2 w = zp[base + lane];
        __half2 hz = *reinterpret_cast<__half2*>(&w.x);
        float2 z = __half22float2(hz);
        float dv = __uint_as_float(w.y);
        int i = cg + lane;
        zxl[wv][i] = z.x;
        zyl[wv][i] = z.y;
        cfl[wv][i] = dv * dv;
    } else if (lane - NPG < nrec4 - nrec) {       // zero padding to multiple of 4
        int i = nrec + (lane - NPG);
        zxl[wv][i] = 0.f;
        zyl[wv][i] = 0.f;
        cfl[wv][i] = 0.f;
    }
    __syncthreads();

    float w0 = W1[lane], w1 = W1[64 + lane], bb = b1[lane];
    float acc = 0.f;
    const float4* px = (const float4*)zxl[wv];
    const float4* py = (const float4*)zyl[wv];
    const float4* pc = (const float4*)cfl[wv];
    int n4 = nrec4 >> 2;
    #pragma unroll 2
    for (int r = 0; r < n4; ++r) {
        float4 X = px[r], Y = py[r], C = pc[r];
        acc += C.x * fmaxf(fmaf(X.x, w0, fmaf(Y.x, w1, bb)), 0.f);
        acc += C.y * fmaxf(fmaf(X.y, w0, fmaf(Y.y, w1, bb)), 0.f);
        acc += C.z * fmaxf(fmaf(X.z, w0, fmaf(Y.z, w1, bb)), 0.f);
        acc += C.w * fmaxf(fmaf(X.w, w0, fmaf(Y.w, w1, bb)), 0.f);
    }
    ps[wv][lane] = acc * (1.0f / (float)NPG);
    __syncthreads();

    float logit = 0.f;
    if (lane < NCLS) {
        logit = bcomb[lane];
        #pragma unroll
        for (int f = 0; f < 64; ++f) logit += ps[wv][f] * wcomb[f * NCLS + lane];
    }
    float m = (lane < NCLS) ? logit : -INFINITY;
    #pragma unroll
    for (int o = 32; o; o >>= 1) m = fmaxf(m, __shfl_xor(m, o, 64));
    float ex = (lane < NCLS) ? expf(logit - m) : 0.f;
    float s = ex;
    #pragma unroll
    for (int o = 32; o; o >>= 1) s += __shfl_xor(s, o, 64);
    if (lane < NCLS) out[g * NCLS + lane] = logit - m - logf(s);
}

// ---------------------------------------------------------------------------
extern "C" void kernel_launch(void* const* d_in, const int* in_sizes, int n_in,
                              void* d_out, int out_size, void* d_ws, size_t ws_size,
                              hipStream_t stream) {
    const float* x   = (const float*)d_in[0];
    const int*   src = (const int*)  d_in[1];
    const int*   dst = (const int*)  d_in[2];
    // d_in[3] = batch (unused; batch == i/21 by construction)
    const float* W1  = (const float*)d_in[4];
    const float* b1  = (const float*)d_in[5];
    const float* W2  = (const float*)d_in[6];
    const float* b2  = (const float*)d_in[7];
    const float* Wfc = (const float*)d_in[8];
    const float* bfc = (const float*)d_in[9];
    float* out = (float*)d_out;

    // workspace carve-up (256B aligned) — total ~41.5 MB
    char* ws = (char*)d_ws;
    size_t off = 0;
    auto carve = [&](size_t bytes) { char* p = ws + off; off += (bytes + 255) & ~(size_t)255; return p; };
    int*          cnt   = (int*)          carve((size_t)NODES * 4);          //  4.2 MB
    int*          ecnt  = (int*)          carve((size_t)GRAPHS * 4);         //  0.2 MB
    int*          eoff  = (int*)          carve((size_t)GRAPHS * 4);         //  0.2 MB
    int*          btot  = (int*)          carve((size_t)NCHUNK * 4);
    int*          bcnt  = (int*)          carve((size_t)NBUCK * 4);
    float*        dinv  = (float*)        carve((size_t)NODES * 4);          //  4.2 MB
    unsigned int* up    = (unsigned int*) carve((size_t)NODES * 4);          //  4.2 MB
    uint2*        zp    = (uint2*)        carve((size_t)NODES * 8);          //  8.4 MB
    int*          pe    = (int*)          carve((size_t)EDGES * 4);          //  8.4 MB
    unsigned int* arena = (unsigned int*) carve((size_t)NBUCK * BCAP * 4);   // 11.5 MB
    float*        wcomb = (float*)        carve((size_t)64 * NCLS * 4);
    float*        bcomb = (float*)        carve((size_t)NCLS * 4);
    (void)ws_size;

    hipMemsetAsync(bcnt, 0, (size_t)NBUCK * 4, stream);

    bucket_k   <<<NBLK_A, NTHR_A, 0, stream>>>(src, dst, bcnt, arena);
    hist_k     <<<NBUCK, 256, 0, stream>>>(bcnt, arena, cnt, ecnt);
    scan1_k    <<<NCHUNK, 1024, 0, stream>>>(ecnt, eoff, btot);
    scan2_k    <<<NCHUNK, 1024, 0, stream>>>(btot, eoff);
    place_k    <<<NBUCK, 256, 0, stream>>>(bcnt, arena, eoff, pe);
    init_nodes <<<(NODES + 255) / 256, 256, 0, stream>>>(x, cnt, dinv, up);
    make_wcomb <<<(64 * NCLS + NCLS + 255) / 256, 256, 0, stream>>>(W2, b2, Wfc, bfc, wcomb, bcomb);
    conv1_k    <<<GRAPHS / 4, 256, 0, stream>>>(pe, eoff, ecnt, up, dinv, zp);
    conv2pool_k<<<GRAPHS / 4, 256, 0, stream>>>(pe, eoff, ecnt, zp, dinv, W1, b1, wcomb, bcomb, out);
}

// Round 11
// 151.000 us; speedup vs baseline: 5.4159x; 1.0094x over previous
//
#include <hip/hip_runtime.h>
#include <hip/hip_fp16.h>
#include <math.h>

// Problem constants (from reference)
#define NODES   1050000
#define EDGES   2100000
#define GRAPHS  50000
#define NPG     21      // nodes per graph
#define NCLS    26
#define REC_MAX 168     // per-graph record cap in conv2pool (cg<=147 stat + 21 self)

// Bucket sort geometry
#define NBUCK   1024
#define GPB     49      // graphs per bucket (1024*49 = 50176 >= 50000)
#define BCAP    2816    // records per bucket cap (E[2051], sigma~45 -> +17 sigma)
#define NBLK_A  256     // blocks for bucket_k
#define NTHR_A  1024    // threads for bucket_k
#define EPB     ((EDGES + NBLK_A - 1) / NBLK_A)   // 8204 edges per block

// ---------------------------------------------------------------------------
// S1: bucket scatter with per-block chunk allocation (near-full-line writes).
// Record: s(21b) << 11 | g_local(6b) << 5 | dloc(5b)   [unsigned!]
__global__ void __launch_bounds__(NTHR_A) bucket_k(const int* __restrict__ src,
                                                   const int* __restrict__ dst,
                                                   int* __restrict__ bcnt,
                                                   unsigned int* __restrict__ arena) {
    __shared__ int hist[NBUCK];
    __shared__ int gbase[NBUCK];
    int tid = threadIdx.x;
    for (int b = tid; b < NBUCK; b += NTHR_A) hist[b] = 0;
    __syncthreads();
    int e0 = blockIdx.x * EPB;
    int e1 = e0 + EPB; if (e1 > EDGES) e1 = EDGES;
    for (int e = e0 + tid; e < e1; e += NTHR_A) {
        int g = dst[e] / NPG;
        atomicAdd(&hist[g / GPB], 1);
    }
    __syncthreads();
    for (int b = tid; b < NBUCK; b += NTHR_A) {
        int h = hist[b];
        gbase[b] = h ? atomicAdd(&bcnt[b], h) : 0;
        hist[b] = 0;                      // reuse as run counter
    }
    __syncthreads();
    for (int e = e0 + tid; e < e1; e += NTHR_A) {
        int s = src[e], d = dst[e];
        int g = d / NPG;
        int b = g / GPB;
        int r = atomicAdd(&hist[b], 1);
        int pos = gbase[b] + r;
        if (pos < BCAP)
            arena[(size_t)b * BCAP + pos] =
                ((unsigned int)s << 11) | ((unsigned int)(g - b * GPB) << 5)
                | (unsigned int)(d - g * NPG);
    }
}

// S2: merged hist + place. Per bucket: node histogram -> cnt, per-graph counts
// -> ecnt, intra-bucket exclusive scan with FIXED base b*BCAP -> eoff (no
// global scan needed), then place records into pe at graph-contiguous spots.
__global__ void __launch_bounds__(256) histplace_k(const int* __restrict__ bcnt,
                                                   const unsigned int* __restrict__ arena,
                                                   int* __restrict__ cnt,
                                                   int* __restrict__ ecnt,
                                                   int* __restrict__ eoff,
                                                   int* __restrict__ pe) {
    __shared__ int h[GPB * NPG];          // 1029 node counters
    __shared__ int gsum[GPB];
    __shared__ int go[GPB];
    int b = blockIdx.x, tid = threadIdx.x;
    for (int i = tid; i < GPB * NPG; i += 256) h[i] = 0;
    __syncthreads();
    int n = bcnt[b]; if (n > BCAP) n = BCAP;
    const unsigned int* ar = arena + (size_t)b * BCAP;
    for (int i = tid; i < n; i += 256) {
        unsigned int rec = ar[i];
        atomicAdd(&h[((rec >> 5) & 63) * NPG + (rec & 31)], 1);
    }
    __syncthreads();
    int node0 = b * GPB * NPG;
    for (int i = tid; i < GPB * NPG; i += 256) {
        int node = node0 + i;
        if (node < NODES) cnt[node] = h[i];
    }
    for (int gl = tid; gl < GPB; gl += 256) {
        int s = 0;
        #pragma unroll
        for (int k = 0; k < NPG; ++k) s += h[gl * NPG + k];
        gsum[gl] = s;
    }
    __syncthreads();
    if (tid == 0) {                       // 49-element serial scan, fixed base
        int run = b * BCAP;
        for (int gl = 0; gl < GPB; ++gl) { go[gl] = run; run += gsum[gl]; }
    }
    __syncthreads();
    int g0 = b * GPB;
    for (int gl = tid; gl < GPB; gl += 256) {
        int g = g0 + gl;
        if (g < GRAPHS) { ecnt[g] = gsum[gl]; eoff[g] = go[gl]; }
    }
    __syncthreads();                      // eoff written before go is mutated
    for (int i = tid; i < n; i += 256) {
        unsigned int rec = ar[i];
        int pos = atomicAdd(&go[(rec >> 5) & 63], 1);
        pe[pos] = (int)(((rec >> 11) << 5) | (rec & 31));
    }
}

// S3: dinv = rsqrt(deg+1); u packed = half2(dinv*x); dk = deg-code (uint8)
__global__ void init_nodes(const float* __restrict__ x, const int* __restrict__ cnt,
                           float* __restrict__ dinv, unsigned int* __restrict__ up,
                           unsigned char* __restrict__ dk) {
    int i = blockIdx.x * blockDim.x + threadIdx.x;
    if (i < NODES) {
        int k = cnt[i] + 1;
        float d = 1.0f / sqrtf((float)k);
        dinv[i] = d;
        dk[i] = (unsigned char)(k > 255 ? 255 : k);
        float2 xv = ((const float2*)x)[i];
        __half2 h = __floats2half2_rn(d * xv.x, d * xv.y);
        up[i] = *reinterpret_cast<unsigned int*>(&h);
    }
}

// S4 (tiny): wcomb = W2@Wfc [64,26]; bcomb = b2@Wfc + bfc [26]
__global__ void make_wcomb(const float* __restrict__ W2, const float* __restrict__ b2,
                           const float* __restrict__ Wfc, const float* __restrict__ bfc,
                           float* __restrict__ wcomb, float* __restrict__ bcomb) {
    int t = blockIdx.x * blockDim.x + threadIdx.x;
    if (t < 64 * NCLS) {
        int f = t / NCLS, c = t % NCLS;
        float acc = 0.f;
        for (int k = 0; k < 128; ++k) acc += W2[f * 128 + k] * Wfc[k * NCLS + c];
        wcomb[t] = acc;
    } else if (t < 64 * NCLS + NCLS) {
        int c = t - 64 * NCLS;
        float acc = bfc[c];
        for (int k = 0; k < 128; ++k) acc += b2[k] * Wfc[k * NCLS + c];
        bcomb[c] = acc;
    }
}

// S5: conv1 per graph — LDS fp32 accumulation of a1 = u[self] + sum u[src];
//     write zh[i] = half2(dinv*a1) only (dinv/dk already in arrays). 4 graphs/block.
__global__ void conv1_k(const int* __restrict__ pe, const int* __restrict__ eoff,
                        const int* __restrict__ ecnt, const unsigned int* __restrict__ up,
                        const float* __restrict__ dinv, unsigned int* __restrict__ zh) {
    __shared__ float a1loc[4][NPG][2];
    int lane = threadIdx.x & 63, wv = threadIdx.x >> 6;
    int g    = blockIdx.x * 4 + wv;
    int base = g * NPG;
    if (lane < 2 * NPG) {                       // self-loop init
        int n = lane >> 1, c = lane & 1;
        unsigned int raw = up[base + n];
        __half2 h = *reinterpret_cast<__half2*>(&raw);
        float2 uv = __half22float2(h);
        a1loc[wv][n][c] = c ? uv.y : uv.x;
    }
    __syncthreads();
    int off = eoff[g], cg = ecnt[g];
    for (int i = lane; i < cg; i += 64) {       // per-lane random gather (high MLP)
        int p = __builtin_nontemporal_load(&pe[off + i]);
        unsigned int raw = up[p >> 5];
        __half2 h = *reinterpret_cast<__half2*>(&raw);
        float2 uv = __half22float2(h);
        atomicAdd(&a1loc[wv][p & 31][0], uv.x);
        atomicAdd(&a1loc[wv][p & 31][1], uv.y);
    }
    __syncthreads();
    if (lane < NPG) {
        float dv = dinv[base + lane];
        __half2 h = __floats2half2_rn(dv * a1loc[wv][lane][0],
                                      dv * a1loc[wv][lane][1]);
        zh[base + lane] = *reinterpret_cast<unsigned int*>(&h);
    }
}

// S6: conv2 + mean-pool + FC + log_softmax fused. ONE wave per graph, 4/block.
// Phase A: per-lane gather from zh (4.2MB, XCD-L2-resident) + dk (1MB);
//          ds from 256-entry LDS rsqrt table; SoA fp32 records in LDS.
// Phase B: 4 records per ds_read_b128 triple, pure fma/max stream.
__global__ void conv2pool_k(const int* __restrict__ pe, const int* __restrict__ eoff,
                            const int* __restrict__ ecnt,
                            const unsigned int* __restrict__ zh,
                            const unsigned char* __restrict__ dk,
                            const float* __restrict__ dinv,
                            const float* __restrict__ W1, const float* __restrict__ b1,
                            const float* __restrict__ wcomb, const float* __restrict__ bcomb,
                            float* __restrict__ out) {
    __shared__ float zxl[4][REC_MAX];
    __shared__ float zyl[4][REC_MAX];
    __shared__ float cfl[4][REC_MAX];
    __shared__ float ps[4][64];
    __shared__ float tbl[256];
    int lane = threadIdx.x & 63, wv = threadIdx.x >> 6;
    if (threadIdx.x < 256)
        tbl[threadIdx.x] = threadIdx.x ? 1.0f / sqrtf((float)threadIdx.x) : 0.f;
    int g    = blockIdx.x * 4 + wv;
    int base = g * NPG;
    int off  = eoff[g];
    int cg   = ecnt[g];
    if (cg > REC_MAX - NPG) cg = REC_MAX - NPG;   // safety clamp
    __syncthreads();                              // tbl ready

    for (int i = lane; i < cg; i += 64) {
        int p = __builtin_nontemporal_load(&pe[off + i]);
        int s = p >> 5;
        unsigned int zraw = zh[s];                // 4B random gather, L2-resident
        float ds = tbl[dk[s]];                    // 1B gather + LDS lookup
        __half2 hz = *reinterpret_cast<__half2*>(&zraw);
        float2 z = __half22float2(hz);
        float dd = dinv[base + (p & 31)];         // graph-local, cache-hot
        zxl[wv][i] = z.x;
        zyl[wv][i] = z.y;
        cfl[wv][i] = ds * dd;
    }
    int nrec  = cg + NPG;
    int nrec4 = (nrec + 3) & ~3;
    if (lane < NPG) {                             // self records, coef = dinv^2
        unsigned int zraw = zh[base + lane];
        __half2 hz = *reinterpret_cast<__half2*>(&zraw);
        float2 z = __half22float2(hz);
        float dv = dinv[base + lane];
        int i = cg + lane;
        zxl[wv][i] = z.x;
        zyl[wv][i] = z.y;
        cfl[wv][i] = dv * dv;
    } else if (lane - NPG < nrec4 - nrec) {       // zero padding to multiple of 4
        int i = nrec + (lane - NPG);
        zxl[wv][i] = 0.f;
        zyl[wv][i] = 0.f;
        cfl[wv][i] = 0.f;
    }
    __syncthreads();

    float w0 = W1[lane], w1 = W1[64 + lane], bb = b1[lane];
    float acc = 0.f;
    const float4* px = (const float4*)zxl[wv];
    const float4* py = (const float4*)zyl[wv];
    const float4* pc = (const float4*)cfl[wv];
    int n4 = nrec4 >> 2;
    #pragma unroll 2
    for (int r = 0; r < n4; ++r) {
        float4 X = px[r], Y = py[r], C = pc[r];
        acc += C.x * fmaxf(fmaf(X.x, w0, fmaf(Y.x, w1, bb)), 0.f);
        acc += C.y * fmaxf(fmaf(X.y, w0, fmaf(Y.y, w1, bb)), 0.f);
        acc += C.z * fmaxf(fmaf(X.z, w0, fmaf(Y.z, w1, bb)), 0.f);
        acc += C.w * fmaxf(fmaf(X.w, w0, fmaf(Y.w, w1, bb)), 0.f);
    }
    ps[wv][lane] = acc * (1.0f / (float)NPG);
    __syncthreads();

    float logit = 0.f;
    if (lane < NCLS) {
        logit = bcomb[lane];
        #pragma unroll
        for (int f = 0; f < 64; ++f) logit += ps[wv][f] * wcomb[f * NCLS + lane];
    }
    float m = (lane < NCLS) ? logit : -INFINITY;
    #pragma unroll
    for (int o = 32; o; o >>= 1) m = fmaxf(m, __shfl_xor(m, o, 64));
    float ex = (lane < NCLS) ? expf(logit - m) : 0.f;
    float s = ex;
    #pragma unroll
    for (int o = 32; o; o >>= 1) s += __shfl_xor(s, o, 64);
    if (lane < NCLS) out[g * NCLS + lane] = logit - m - logf(s);
}

// ---------------------------------------------------------------------------
extern "C" void kernel_launch(void* const* d_in, const int* in_sizes, int n_in,
                              void* d_out, int out_size, void* d_ws, size_t ws_size,
                              hipStream_t stream) {
    const float* x   = (const float*)d_in[0];
    const int*   src = (const int*)  d_in[1];
    const int*   dst = (const int*)  d_in[2];
    // d_in[3] = batch (unused; batch == i/21 by construction)
    const float* W1  = (const float*)d_in[4];
    const float* b1  = (const float*)d_in[5];
    const float* W2  = (const float*)d_in[6];
    const float* b2  = (const float*)d_in[7];
    const float* Wfc = (const float*)d_in[8];
    const float* bfc = (const float*)d_in[9];
    float* out = (float*)d_out;

    // workspace carve-up (256B aligned) — total ~41.4 MB
    char* ws = (char*)d_ws;
    size_t off = 0;
    auto carve = [&](size_t bytes) { char* p = ws + off; off += (bytes + 255) & ~(size_t)255; return p; };
    int*           cnt   = (int*)           carve((size_t)NODES * 4);          //  4.2 MB
    int*           ecnt  = (int*)           carve((size_t)GRAPHS * 4);         //  0.2 MB
    int*           eoff  = (int*)           carve((size_t)GRAPHS * 4);         //  0.2 MB
    int*           bcnt  = (int*)           carve((size_t)NBUCK * 4);
    float*         dinv  = (float*)         carve((size_t)NODES * 4);          //  4.2 MB
    unsigned int*  up    = (unsigned int*)  carve((size_t)NODES * 4);          //  4.2 MB
    unsigned int*  zh    = (unsigned int*)  carve((size_t)NODES * 4);          //  4.2 MB
    unsigned char* dk    = (unsigned char*) carve((size_t)NODES);              //  1.05 MB
    int*           pe    = (int*)           carve((size_t)NBUCK * BCAP * 4);   // 11.5 MB
    unsigned int*  arena = (unsigned int*)  carve((size_t)NBUCK * BCAP * 4);   // 11.5 MB
    float*         wcomb = (float*)         carve((size_t)64 * NCLS * 4);
    float*         bcomb = (float*)         carve((size_t)NCLS * 4);
    (void)ws_size;

    hipMemsetAsync(bcnt, 0, (size_t)NBUCK * 4, stream);

    bucket_k   <<<NBLK_A, NTHR_A, 0, stream>>>(src, dst, bcnt, arena);
    histplace_k<<<NBUCK, 256, 0, stream>>>(bcnt, arena, cnt, ecnt, eoff, pe);
    init_nodes <<<(NODES + 255) / 256, 256, 0, stream>>>(x, cnt, dinv, up, dk);
    make_wcomb <<<(64 * NCLS + NCLS + 255) / 256, 256, 0, stream>>>(W2, b2, Wfc, bfc, wcomb, bcomb);
    conv1_k    <<<GRAPHS / 4, 256, 0, stream>>>(pe, eoff, ecnt, up, dinv, zh);
    conv2pool_k<<<GRAPHS / 4, 256, 0, stream>>>(pe, eoff, ecnt, zh, dk, dinv, W1, b1, wcomb, bcomb, out);
}